// Round 4
// baseline (412.658 us; speedup 1.0000x reference)
//
#include <hip/hip_runtime.h>

#define NUM_ENT 10000
#define NUM_REL 50
#define HID 64
#define NTRIP 500000

typedef __attribute__((ext_vector_type(8))) short short8;
typedef __attribute__((ext_vector_type(4))) float f32x4;

// bf16 helpers (RNE)
static __device__ __forceinline__ unsigned short f2bf(float x) {
    unsigned u = __float_as_uint(x);
    return (unsigned short)((u + 0x7FFFu + ((u >> 16) & 1u)) >> 16);
}
static __device__ __forceinline__ float bf2f(unsigned short b) {
    return __uint_as_float((unsigned)b << 16);
}
static __device__ __forceinline__ short8 ld8(const unsigned short* p) {
    return *(const short8*)p;
}

// ============================================================
// bucketing: bins keyed (r/GR)*NUM_ENT + t
// ============================================================

__global__ __launch_bounds__(256) void k_thist(const int* __restrict__ r,
                                               const int* __restrict__ t,
                                               int* __restrict__ bins, int gsz) {
    int i = blockIdx.x * 256 + threadIdx.x;
    if (i < NTRIP) atomicAdd(&bins[(r[i] / gsz) * NUM_ENT + t[i]], 1);
}

__global__ __launch_bounds__(1024) void k_scan(int* __restrict__ bins,
                                               int* __restrict__ toff, int nbins) {
    __shared__ int wsum[16];
    int tid = threadIdx.x, lane = tid & 63, w = tid >> 6;
    int running = 0;
    for (int base = 0; base < nbins; base += 1024) {
        int i = base + tid;
        int s = (i < nbins) ? bins[i] : 0;
        int v = s;
        for (int off = 1; off < 64; off <<= 1) {
            int u = __shfl_up(v, off);
            if (lane >= off) v += u;
        }
        if (lane == 63) wsum[w] = v;
        __syncthreads();
        int woff = 0, tot = 0;
#pragma unroll
        for (int k = 0; k < 16; ++k) {
            int x = wsum[k];
            woff += (k < w) ? x : 0;
            tot += x;
        }
        int excl = running + woff + (v - s);
        if (i < nbins) { toff[i] = excl; bins[i] = excl; }
        running += tot;
        __syncthreads();
    }
    if (tid == 0) toff[nbins] = running;
}

__global__ __launch_bounds__(256) void k_tscatter(const int* __restrict__ h,
                                                  const int* __restrict__ r,
                                                  const int* __restrict__ t,
                                                  int* __restrict__ cur,
                                                  unsigned* __restrict__ bucket2, int gsz) {
    int i = blockIdx.x * 256 + threadIdx.x;
    if (i < NTRIP) {
        int rr = r[i];
        int pos = atomicAdd(&cur[(rr / gsz) * NUM_ENT + t[i]], 1);
        bucket2[pos] = (unsigned)h[i] | ((unsigned)rr << 14);
    }
}

// ============================================================
// small prep kernels
// ============================================================

__global__ void k_diag0(const float* __restrict__ Wmr0, float* __restrict__ diag0) {
    int i = blockIdx.x * 256 + threadIdx.x;
    if (i < NUM_REL * HID) diag0[i] = Wmr0[(size_t)i * NUM_REL + (i >> 6)];
}

// U0[e,d] = Wres0[d,e]
__global__ void k_init_u0(const float* __restrict__ Wres0, float* __restrict__ U0) {
    __shared__ float tile[64][65];
    int e0 = blockIdx.x * 64;
    for (int i = threadIdx.x; i < 64 * 64; i += 256) {
        int dd = i >> 6, xx = i & 63;
        if (e0 + xx < NUM_ENT) tile[xx][dd] = Wres0[dd * NUM_ENT + e0 + xx];
    }
    __syncthreads();
    for (int i = threadIdx.x; i < 64 * 64; i += 256) {
        int ee = i >> 6, dd = i & 63;
        if (e0 + ee < NUM_ENT) U0[(e0 + ee) * HID + dd] = tile[ee][dd];
    }
}

// diag1[r,d]; outrel[r,d]
__global__ void k_rel(const float* __restrict__ Wpr0, const float* __restrict__ Wmr1,
                      const float* __restrict__ Wpr1, float* __restrict__ diag1,
                      float* __restrict__ outrel) {
    __shared__ float wp[HID];
    int rr = blockIdx.x, d = threadIdx.x;
    wp[d] = Wpr0[d * NUM_REL + rr];
    __syncthreads();
    float s1 = 0.0f, s2 = 0.0f;
    const float* wmr = Wmr1 + (size_t)(rr * HID + d) * HID;
    const float* wpr = Wpr1 + d * HID;
    for (int k = 0; k < HID; k++) { s1 += wp[k] * wmr[k]; s2 += wp[k] * wpr[k]; }
    diag1[rr * HID + d] = s1;
    outrel[rr * HID + d] = s2;
}

// WTb slots (4096 bf16 each): 0..49 = Wme1[r][d][k]; 50 = Wres1[d][k];
// 51+g = diagT_g[d][k] = diag1[g*GR+k][d] (k<grels else 0)
__global__ __launch_bounds__(256) void k_wconv(const float* __restrict__ Wme1,
                                               const float* __restrict__ Wres1,
                                               const float* __restrict__ diag1,
                                               unsigned short* __restrict__ WTb, int GR) {
    int b = blockIdx.x;
    unsigned short* dst = WTb + (size_t)b * 4096;
    if (b < 50) {
        const float* src = Wme1 + (size_t)b * 4096;
        for (int i = threadIdx.x; i < 4096; i += 256) dst[i] = f2bf(src[i]);
    } else if (b == 50) {
        for (int i = threadIdx.x; i < 4096; i += 256) dst[i] = f2bf(Wres1[i]);
    } else {
        int g = b - 51;
        for (int i = threadIdx.x; i < 4096; i += 256) {
            int d = i >> 6, k = i & 63;
            int rr = g * GR + k;
            dst[i] = (k < GR && rr < NUM_REL) ? f2bf(diag1[rr * 64 + d]) : (unsigned short)0;
        }
    }
}

// ============================================================
// layer 0: transpose Wme0 chunk -> P (bf16), gather-scatter into U0
// ============================================================

// P[e*RSp + rl*64 + d] = bf16(Wme0[(rr*64+d)*NUM_ENT + e]); grid (grels, netiles)
__global__ __launch_bounds__(256) void k_transpose(const float* __restrict__ W,
                                                   unsigned short* __restrict__ P,
                                                   int r0, int RSp) {
    __shared__ float tile[64][65];
    int rl = blockIdx.x;
    int rr = r0 + rl;
    int e0 = blockIdx.y * 64;
    int tid = threadIdx.x;
    for (int i = tid; i < 4096; i += 256) {
        int dd = i >> 6, xx = i & 63;
        int e = e0 + xx;
        tile[dd][xx] = (e < NUM_ENT) ? W[(size_t)(rr * HID + dd) * NUM_ENT + e] : 0.f;
    }
    __syncthreads();
    for (int i = tid; i < 4096; i += 256) {
        int ee = i >> 6, dd = i & 63;
        int e = e0 + ee;
        if (e < NUM_ENT) P[(size_t)e * RSp + (size_t)rl * 64 + dd] = f2bf(tile[dd][ee]);
    }
}

// wave per tail: target[e,:] += sum_j (P[h_j, rl_j, :] + diag0[rr_j,:]);
// last group: lrelu and write Abf
__global__ __launch_bounds__(256) void k_scatter(const unsigned short* __restrict__ table,
                                                 const float* __restrict__ diag,
                                                 const int* __restrict__ toff,
                                                 const unsigned* __restrict__ bucket2,
                                                 float* __restrict__ target,
                                                 unsigned short* __restrict__ Abf,
                                                 int RSp, int g0, int applyAct) {
    int e = __builtin_amdgcn_readfirstlane(blockIdx.x * 4 + (threadIdx.x >> 6));
    int d = threadIdx.x & 63;
    if (e >= NUM_ENT) return;
    int j0 = toff[e], j1 = toff[e + 1];
    float acc = 0.f, acc2 = 0.f;
    int j = j0;
    for (; j + 2 <= j1; j += 2) {
        unsigned hr0 = bucket2[j], hr1 = bucket2[j + 1];
        int h0 = hr0 & 16383, ra = hr0 >> 14;
        int h1 = hr1 & 16383, rb = hr1 >> 14;
        float v0 = bf2f(table[(size_t)h0 * RSp + (size_t)(ra - g0) * 64 + d]);
        float v1 = bf2f(table[(size_t)h1 * RSp + (size_t)(rb - g0) * 64 + d]);
        acc  += v0 + diag[ra * 64 + d];
        acc2 += v1 + diag[rb * 64 + d];
    }
    if (j < j1) {
        unsigned hr0 = bucket2[j];
        int h0 = hr0 & 16383, ra = hr0 >> 14;
        acc += bf2f(table[(size_t)h0 * RSp + (size_t)(ra - g0) * 64 + d]) + diag[ra * 64 + d];
    }
    acc += acc2;
    float v = target[e * HID + d] + acc;
    if (applyAct) {
        v = (v >= 0.f) ? v : 0.01f * v;
        Abf[e * HID + d] = f2bf(v);
    }
    target[e * HID + d] = v;
}

// ============================================================
// layer 1: aggregate (LDS, atomic ds_add) then accumulate-GEMM (MFMA)
// ============================================================

// wave per tail: G[e][rl][:] = sum_{j: r=r0+rl} A[h_j][:]; G[e][GR][rl] = count
template <int GR>
__global__ __launch_bounds__(256) void k_aggr(const float* __restrict__ A,
                                              const int* __restrict__ toff,
                                              const unsigned* __restrict__ bucket2,
                                              unsigned short* __restrict__ G,
                                              int r0, int RS1) {
    __shared__ float lds[4][(GR + 1) * 64];
    int w = threadIdx.x >> 6;
    int d = threadIdx.x & 63;
    float* Gw = lds[w];
#pragma unroll 4
    for (int s = 0; s <= GR; ++s) Gw[s * 64 + d] = 0.f;
    int e = blockIdx.x * 4 + w;
    int j0 = toff[e], j1 = toff[e + 1];
    int j = j0;
    for (; j + 2 <= j1; j += 2) {
        unsigned hr0 = bucket2[j], hr1 = bucket2[j + 1];
        int h0 = hr0 & 16383, rl0 = (int)(hr0 >> 14) - r0;
        int h1 = hr1 & 16383, rl1 = (int)(hr1 >> 14) - r0;
        float a0 = A[(size_t)h0 * HID + d];
        float a1 = A[(size_t)h1 * HID + d];
        atomicAdd(&Gw[rl0 * 64 + d], a0);
        atomicAdd(&Gw[rl1 * 64 + d], a1);
        if (d == rl0) atomicAdd(&Gw[GR * 64 + rl0], 1.f);
        if (d == rl1) atomicAdd(&Gw[GR * 64 + rl1], 1.f);
    }
    if (j < j1) {
        unsigned hr0 = bucket2[j];
        int h0 = hr0 & 16383, rl0 = (int)(hr0 >> 14) - r0;
        float a0 = A[(size_t)h0 * HID + d];
        atomicAdd(&Gw[rl0 * 64 + d], a0);
        if (d == rl0) atomicAdd(&Gw[GR * 64 + rl0], 1.f);
    }
    __builtin_amdgcn_s_barrier();  // cheap wave-local ordering not needed; LDS same-wave is ordered
    unsigned short* Ge = G + (size_t)e * RS1;
#pragma unroll 4
    for (int s = 0; s <= GR; ++s) Ge[s * 64 + d] = f2bf(Gw[s * 64 + d]);
}

// out[e][d] (+)= sum_{rl<grels} G[e][rl][:] . WTb[r0+rl][d][:]
//             + G[e][GR][:] . WTb[51+g][d][:]          (cnt * diag1^T)
//             + (g==0) Abf[e][:] . WTb[50][d][:]       (A @ Wres1^T)
// last group: += out, lrelu
__global__ __launch_bounds__(256) void k_gemmAcc(const unsigned short* __restrict__ G,
                                                 const unsigned short* __restrict__ WTb,
                                                 const unsigned short* __restrict__ Abf,
                                                 float* __restrict__ out,
                                                 int r0, int grels, int GR, int RS1,
                                                 int first, int last) {
    int e0 = blockIdx.x * 64;
    int w = (int)threadIdx.x >> 6;
    int lane = (int)threadIdx.x & 63;
    int lrow = lane & 15;
    int lk8 = (lane >> 4) * 8;
    int row = e0 + w * 16 + lrow;
    int rowc = row < NUM_ENT ? row : NUM_ENT - 1;
    const unsigned short* Gr = G + (size_t)rowc * RS1;

    f32x4 acc[4] = {};
    for (int rl = 0; rl < grels; ++rl) {
        const unsigned short* wb = WTb + (size_t)(r0 + rl) * 4096;
        short8 a0 = ld8(Gr + rl * 64 + lk8);
        short8 a1 = ld8(Gr + rl * 64 + 32 + lk8);
#pragma unroll
        for (int t = 0; t < 4; ++t) {
            const unsigned short* wd = wb + (t * 16 + lrow) * 64;
            short8 b0 = ld8(wd + lk8);
            short8 b1 = ld8(wd + 32 + lk8);
            acc[t] = __builtin_amdgcn_mfma_f32_16x16x32_bf16(a0, b0, acc[t], 0, 0, 0);
            acc[t] = __builtin_amdgcn_mfma_f32_16x16x32_bf16(a1, b1, acc[t], 0, 0, 0);
        }
    }
    {   // cnt * diag1^T
        int g = (r0 == 0 && grels == GR && GR == NUM_REL) ? 0 : (r0 / GR);
        const unsigned short* wb = WTb + (size_t)(51 + g) * 4096;
        short8 a0 = ld8(Gr + GR * 64 + lk8);
        short8 a1 = ld8(Gr + GR * 64 + 32 + lk8);
#pragma unroll
        for (int t = 0; t < 4; ++t) {
            const unsigned short* wd = wb + (t * 16 + lrow) * 64;
            short8 b0 = ld8(wd + lk8);
            short8 b1 = ld8(wd + 32 + lk8);
            acc[t] = __builtin_amdgcn_mfma_f32_16x16x32_bf16(a0, b0, acc[t], 0, 0, 0);
            acc[t] = __builtin_amdgcn_mfma_f32_16x16x32_bf16(a1, b1, acc[t], 0, 0, 0);
        }
    }
    if (first) {  // A @ Wres1^T
        const unsigned short* wb = WTb + (size_t)50 * 4096;
        short8 a0 = ld8(Abf + (size_t)rowc * 64 + lk8);
        short8 a1 = ld8(Abf + (size_t)rowc * 64 + 32 + lk8);
#pragma unroll
        for (int t = 0; t < 4; ++t) {
            const unsigned short* wd = wb + (t * 16 + lrow) * 64;
            short8 b0 = ld8(wd + lk8);
            short8 b1 = ld8(wd + 32 + lk8);
            acc[t] = __builtin_amdgcn_mfma_f32_16x16x32_bf16(a0, b0, acc[t], 0, 0, 0);
            acc[t] = __builtin_amdgcn_mfma_f32_16x16x32_bf16(a1, b1, acc[t], 0, 0, 0);
        }
    }
    int hi = lane >> 4;
#pragma unroll
    for (int t = 0; t < 4; ++t) {
#pragma unroll
        for (int q = 0; q < 4; ++q) {
            int eo = e0 + w * 16 + hi * 4 + q;
            if (eo < NUM_ENT) {
                int idx = eo * 64 + t * 16 + lrow;
                float v = acc[t][q];
                if (!first) v += out[idx];
                if (last) v = (v >= 0.f) ? v : 0.01f * v;
                out[idx] = v;
            }
        }
    }
}

// ============================================================
// fallback path (round-1 atomic kernels) — used only if ws too small
// ============================================================

__global__ void k_hist(const int* __restrict__ r, int* __restrict__ hist) {
    __shared__ int lh[NUM_REL];
    int tid = threadIdx.x;
    if (tid < NUM_REL) lh[tid] = 0;
    __syncthreads();
    int i = blockIdx.x * blockDim.x + tid;
    if (i < NTRIP) atomicAdd(&lh[r[i]], 1);
    __syncthreads();
    if (tid < NUM_REL && lh[tid] > 0) atomicAdd(&hist[tid], lh[tid]);
}

__global__ void k_scan_small(const int* __restrict__ hist, int* __restrict__ off,
                             int* __restrict__ cur) {
    if (threadIdx.x == 0 && blockIdx.x == 0) {
        int s = 0;
        for (int i = 0; i < NUM_REL; i++) { off[i] = s; cur[i] = s; s += hist[i]; }
        off[NUM_REL] = s;
    }
}

__global__ void k_bucket(const int* __restrict__ h, const int* __restrict__ r,
                         const int* __restrict__ t, int* __restrict__ cur,
                         int2* __restrict__ bucket) {
    __shared__ int lcnt[NUM_REL];
    __shared__ int lbase[NUM_REL];
    int tid = threadIdx.x;
    if (tid < NUM_REL) lcnt[tid] = 0;
    __syncthreads();
    int i = blockIdx.x * blockDim.x + tid;
    int rr = -1, lpos = 0;
    if (i < NTRIP) { rr = r[i]; lpos = atomicAdd(&lcnt[rr], 1); }
    __syncthreads();
    if (tid < NUM_REL && lcnt[tid] > 0) lbase[tid] = atomicAdd(&cur[tid], lcnt[tid]);
    __syncthreads();
    if (i < NTRIP) bucket[lbase[rr] + lpos] = make_int2(h[i], t[i]);
}

__global__ void k_l0(const float* __restrict__ Wme0, const float* __restrict__ Wmr0,
                     const int* __restrict__ off, const int2* __restrict__ bucket,
                     float* __restrict__ U0) {
    __shared__ float row[NUM_ENT];
    int rr = blockIdx.x >> 6;
    int d  = blockIdx.x & 63;
    const float4* src4 = (const float4*)(Wme0 + (size_t)(rr * HID + d) * NUM_ENT);
    float4* row4 = (float4*)row;
    for (int i = threadIdx.x; i < NUM_ENT / 4; i += blockDim.x) row4[i] = src4[i];
    __syncthreads();
    float wd0 = Wmr0[(size_t)(rr * HID + d) * NUM_REL + rr];
    int b0 = off[rr], b1 = off[rr + 1];
    for (int i = b0 + threadIdx.x; i < b1; i += blockDim.x) {
        int2 ht = bucket[i];
        atomicAdd(&U0[(size_t)ht.y * HID + d], row[ht.x] + wd0);
    }
}

__global__ void k_lrelu(float* __restrict__ x, int n) {
    int i = blockIdx.x * blockDim.x + threadIdx.x;
    if (i < n) { float v = x[i]; x[i] = v >= 0.0f ? v : 0.01f * v; }
}

__global__ void k_init_u1(const float* __restrict__ A, const float* __restrict__ Wres1,
                          float* __restrict__ out) {
    __shared__ float W[HID][HID + 1];
    int tid = threadIdx.x;
    for (int i = tid; i < HID * HID; i += 256) W[i >> 6][i & 63] = Wres1[i];
    __syncthreads();
    int g = blockIdx.x * 256 + tid;
    int e = g >> 6, d = g & 63;
    if (e >= NUM_ENT) return;
    const float4* arow = (const float4*)(A + (size_t)e * HID);
    float acc = 0.0f;
#pragma unroll
    for (int k4 = 0; k4 < 16; k4++) {
        float4 a = arow[k4];
        acc = fmaf(a.x, W[d][k4 * 4 + 0], acc);
        acc = fmaf(a.y, W[d][k4 * 4 + 1], acc);
        acc = fmaf(a.z, W[d][k4 * 4 + 2], acc);
        acc = fmaf(a.w, W[d][k4 * 4 + 3], acc);
    }
    out[g] = acc;
}

#define L1_CHUNKS 16
__global__ void k_l1(const float* __restrict__ A, const float* __restrict__ Wme1,
                     const int* __restrict__ off, const int2* __restrict__ bucket,
                     const float* __restrict__ diag1, float* __restrict__ out) {
    int rr = blockIdx.x / L1_CHUNKS;
    int chunk = blockIdx.x % L1_CHUNKS;
    int b0 = off[rr], b1 = off[rr + 1];
    for (int i = b0 + chunk * 256 + (int)threadIdx.x; i < b1; i += L1_CHUNKS * 256) {
        int2 ht = bucket[i];
        const float4* arow = (const float4*)(A + (size_t)ht.x * HID);
        float4 a[16];
#pragma unroll
        for (int j = 0; j < 16; j++) a[j] = arow[j];
        float* op = out + (size_t)ht.y * HID;
#pragma unroll 4
        for (int d = 0; d < HID; d++) {
            const float4* m4 = (const float4*)(Wme1 + (size_t)(rr * HID + d) * HID);
            float acc = diag1[rr * HID + d];
#pragma unroll
            for (int k = 0; k < 16; k++) {
                float4 m = m4[k];
                acc = fmaf(a[k].x, m.x, acc);
                acc = fmaf(a[k].y, m.y, acc);
                acc = fmaf(a[k].z, m.z, acc);
                acc = fmaf(a[k].w, m.w, acc);
            }
            atomicAdd(op + d, acc);
        }
    }
}

// ============================================================
// launch
// ============================================================

static inline size_t align_up(size_t x, size_t a) { return (x + a - 1) & ~(a - 1); }

extern "C" void kernel_launch(void* const* d_in, const int* in_sizes, int n_in,
                              void* d_out, int out_size, void* d_ws, size_t ws_size,
                              hipStream_t stream) {
    const float* Wres0 = (const float*)d_in[0];
    const float* Wme0  = (const float*)d_in[1];
    const float* Wmr0  = (const float*)d_in[2];
    const float* Wpr0  = (const float*)d_in[3];
    const float* Wres1 = (const float*)d_in[4];
    const float* Wme1  = (const float*)d_in[5];
    const float* Wmr1  = (const float*)d_in[6];
    const float* Wpr1  = (const float*)d_in[7];
    const int* h = (const int*)d_in[8];
    const int* r = (const int*)d_in[9];
    const int* t = (const int*)d_in[10];
    float* out = (float*)d_out;  // [640000 ent | 3200 rel]

    char* ws = (char*)d_ws;
    const int nbt = (NTRIP + 255) / 256;       // 1954
    const int net = (NUM_ENT + 63) / 64;       // 157

    // pick GR = 50 (1 group) if it fits, else 25 (2 groups), else fallback
    int GR = 0, ngroups = 0;
    size_t oUB = 0, oB2 = 0, oToff = 0, oBins = 0, oU0 = 0, oAbf = 0, oD0 = 0,
           oD1 = 0, oWT = 0;
    for (int gr = NUM_REL; gr >= 25; gr -= 25) {
        int ng = NUM_REL / gr;
        size_t p = 0;
        size_t UB_  = p; p += align_up((size_t)(gr + 1) * 64 * NUM_ENT * 2, 256);
        size_t B2_  = p; p += align_up((size_t)NTRIP * 4, 256);
        size_t Tf_  = p; p += align_up(((size_t)ng * NUM_ENT + 1) * 4, 256);
        size_t Bn_  = p; p += align_up((size_t)ng * NUM_ENT * 4, 256);
        size_t U0_  = p; p += align_up((size_t)NUM_ENT * HID * 4, 256);
        size_t Ab_  = p; p += align_up((size_t)NUM_ENT * HID * 2, 256);
        size_t D0_  = p; p += align_up((size_t)NUM_REL * HID * 4, 256);
        size_t D1_  = p; p += align_up((size_t)NUM_REL * HID * 4, 256);
        size_t WT_  = p; p += align_up((size_t)53 * 4096 * 2, 256);
        if (p <= ws_size) {
            GR = gr; ngroups = ng;
            oUB = UB_; oB2 = B2_; oToff = Tf_; oBins = Bn_; oU0 = U0_; oAbf = Ab_;
            oD0 = D0_; oD1 = D1_; oWT = WT_;
            break;
        }
    }

    if (GR >= 25) {
        unsigned short* UB    = (unsigned short*)(ws + oUB);   // P then G
        unsigned* bucket2     = (unsigned*)(ws + oB2);
        int*      toff        = (int*)(ws + oToff);
        int*      bins        = (int*)(ws + oBins);
        float*    U0          = (float*)(ws + oU0);
        unsigned short* Abf   = (unsigned short*)(ws + oAbf);
        float*    diag0       = (float*)(ws + oD0);
        float*    diag1       = (float*)(ws + oD1);
        unsigned short* WTb   = (unsigned short*)(ws + oWT);
        int nbins = ngroups * NUM_ENT;
        int RSp = GR * 64;
        int RS1 = (GR + 1) * 64;

        hipMemsetAsync(bins, 0, (size_t)nbins * 4, stream);
        k_thist<<<nbt, 256, 0, stream>>>(r, t, bins, GR);
        k_scan<<<1, 1024, 0, stream>>>(bins, toff, nbins);
        k_tscatter<<<nbt, 256, 0, stream>>>(h, r, t, bins, bucket2, GR);

        k_diag0<<<(NUM_REL * HID + 255) / 256, 256, 0, stream>>>(Wmr0, diag0);
        k_init_u0<<<net, 256, 0, stream>>>(Wres0, U0);

        // ---- layer 0 ----
        for (int g = 0; g < ngroups; ++g) {
            k_transpose<<<dim3(GR, net), 256, 0, stream>>>(Wme0, UB, g * GR, RSp);
            k_scatter<<<(NUM_ENT + 3) / 4, 256, 0, stream>>>(
                UB, diag0, toff + (size_t)g * NUM_ENT, bucket2, U0, Abf, RSp, g * GR,
                (g == ngroups - 1) ? 1 : 0);
        }
        // U0 = A (fp32, activated); Abf = A (bf16)

        k_rel<<<NUM_REL, HID, 0, stream>>>(Wpr0, Wmr1, Wpr1, diag1, out + NUM_ENT * HID);
        k_wconv<<<51 + ngroups, 256, 0, stream>>>(Wme1, Wres1, diag1, WTb, GR);

        // ---- layer 1 ----
        for (int g = 0; g < ngroups; ++g) {
            if (GR == 50)
                k_aggr<50><<<NUM_ENT / 4, 256, 0, stream>>>(
                    U0, toff + (size_t)g * NUM_ENT, bucket2, UB, g * GR, RS1);
            else
                k_aggr<25><<<NUM_ENT / 4, 256, 0, stream>>>(
                    U0, toff + (size_t)g * NUM_ENT, bucket2, UB, g * GR, RS1);
            k_gemmAcc<<<net, 256, 0, stream>>>(
                UB, WTb, Abf, out, g * GR, GR, GR, RS1,
                (g == 0) ? 1 : 0, (g == ngroups - 1) ? 1 : 0);
        }
        return;
    }

    // ---------- fallback: round-1 atomic path ----------
    {
        int2*  bucket = (int2*)ws;                    // 4,000,000 B
        float* U0     = (float*)(ws + 4000000);       // 2,560,000 B
        float* diag1  = (float*)(ws + 6560000);       // 12,800 B
        int*   hist   = (int*)(ws + 6572800);
        int*   off    = (int*)(ws + 6573056);
        int*   cur    = (int*)(ws + 6573312);

        hipMemsetAsync(hist, 0, NUM_REL * sizeof(int), stream);
        k_hist<<<nbt, 256, 0, stream>>>(r, hist);
        k_scan_small<<<1, 64, 0, stream>>>(hist, off, cur);
        k_bucket<<<nbt, 256, 0, stream>>>(h, r, t, cur, bucket);

        k_init_u0<<<net, 256, 0, stream>>>(Wres0, U0);
        k_l0<<<NUM_REL * HID, 256, 0, stream>>>(Wme0, Wmr0, off, bucket, U0);
        k_lrelu<<<(NUM_ENT * HID + 255) / 256, 256, 0, stream>>>(U0, NUM_ENT * HID);

        k_rel<<<NUM_REL, HID, 0, stream>>>(Wpr0, Wmr1, Wpr1, diag1, out + NUM_ENT * HID);
        k_init_u1<<<(NUM_ENT * HID) / 256, 256, 0, stream>>>(U0, Wres1, out);
        k_l1<<<NUM_REL * L1_CHUNKS, 256, 0, stream>>>(U0, Wme1, off, bucket, diag1, out);
        k_lrelu<<<(NUM_ENT * HID + 255) / 256, 256, 0, stream>>>(out, NUM_ENT * HID);
    }
}

// Round 5
// 244.720 us; speedup vs baseline: 1.6862x; 1.6862x over previous
//
#include <hip/hip_runtime.h>

#define NUM_ENT 10000
#define NUM_REL 50
#define HID 64
#define NTRIP 500000

typedef __attribute__((ext_vector_type(8))) short short8;
typedef __attribute__((ext_vector_type(4))) float f32x4;

// bf16 helpers (RNE)
static __device__ __forceinline__ unsigned short f2bf(float x) {
    unsigned u = __float_as_uint(x);
    return (unsigned short)((u + 0x7FFFu + ((u >> 16) & 1u)) >> 16);
}
static __device__ __forceinline__ float bf2f(unsigned short b) {
    return __uint_as_float((unsigned)b << 16);
}
static __device__ __forceinline__ short8 ld8(const unsigned short* p) {
    return *(const short8*)p;
}

// ============================================================
// bucketing: bins keyed (r/GR)*NUM_ENT + t ; bucket stores element offset
// off = h*RS + (r%GR)*64 (same table geometry for layer0 P and layer1 B)
// ============================================================

__global__ __launch_bounds__(256) void k_thist(const int* __restrict__ r,
                                               const int* __restrict__ t,
                                               int* __restrict__ bins, int gsz) {
    int i = blockIdx.x * 256 + threadIdx.x;
    if (i < NTRIP) atomicAdd(&bins[(r[i] / gsz) * NUM_ENT + t[i]], 1);
}

__global__ __launch_bounds__(1024) void k_scan(int* __restrict__ bins,
                                               int* __restrict__ toff, int nbins) {
    __shared__ int wsum[16];
    int tid = threadIdx.x, lane = tid & 63, w = tid >> 6;
    int running = 0;
    for (int base = 0; base < nbins; base += 1024) {
        int i = base + tid;
        int s = (i < nbins) ? bins[i] : 0;
        int v = s;
        for (int off = 1; off < 64; off <<= 1) {
            int u = __shfl_up(v, off);
            if (lane >= off) v += u;
        }
        if (lane == 63) wsum[w] = v;
        __syncthreads();
        int woff = 0, tot = 0;
#pragma unroll
        for (int k = 0; k < 16; ++k) {
            int x = wsum[k];
            woff += (k < w) ? x : 0;
            tot += x;
        }
        int excl = running + woff + (v - s);
        if (i < nbins) { toff[i] = excl; bins[i] = excl; }
        running += tot;
        __syncthreads();
    }
    if (tid == 0) toff[nbins] = running;
}

__global__ __launch_bounds__(256) void k_tscatter(const int* __restrict__ h,
                                                  const int* __restrict__ r,
                                                  const int* __restrict__ t,
                                                  int* __restrict__ cur,
                                                  unsigned* __restrict__ bucket2,
                                                  int gsz, int RS) {
    int i = blockIdx.x * 256 + threadIdx.x;
    if (i < NTRIP) {
        int rr = r[i];
        int g = rr / gsz;
        int pos = atomicAdd(&cur[g * NUM_ENT + t[i]], 1);
        bucket2[pos] = (unsigned)h[i] * (unsigned)RS + (unsigned)(rr - g * gsz) * 64u;
    }
}

// ============================================================
// small prep kernels
// ============================================================

// diag0[r*64+d] = Wmr0[(r*64+d)*50 + r]
__global__ void k_diag0(const float* __restrict__ Wmr0, float* __restrict__ diag0) {
    int i = blockIdx.x * 256 + threadIdx.x;
    if (i < NUM_REL * HID) diag0[i] = Wmr0[(size_t)i * NUM_REL + (i >> 6)];
}

// U0[e,d] = Wres0[d,e]
__global__ void k_init_u0(const float* __restrict__ Wres0, float* __restrict__ U0) {
    __shared__ float tile[64][65];
    int e0 = blockIdx.x * 64;
    for (int i = threadIdx.x; i < 64 * 64; i += 256) {
        int dd = i >> 6, xx = i & 63;
        if (e0 + xx < NUM_ENT) tile[xx][dd] = Wres0[dd * NUM_ENT + e0 + xx];
    }
    __syncthreads();
    for (int i = threadIdx.x; i < 64 * 64; i += 256) {
        int ee = i >> 6, dd = i & 63;
        if (e0 + ee < NUM_ENT) U0[(e0 + ee) * HID + dd] = tile[ee][dd];
    }
}

// diag1[r,d] = sum_k Wpr0[k,r]*Wmr1[(r*64+d),k]; outrel[r,d] = sum_k Wpr0[k,r]*Wpr1[d,k]
__global__ void k_rel(const float* __restrict__ Wpr0, const float* __restrict__ Wmr1,
                      const float* __restrict__ Wpr1, float* __restrict__ diag1,
                      float* __restrict__ outrel) {
    __shared__ float wp[HID];
    int rr = blockIdx.x, d = threadIdx.x;
    wp[d] = Wpr0[d * NUM_REL + rr];
    __syncthreads();
    float s1 = 0.0f, s2 = 0.0f;
    const float* wmr = Wmr1 + (size_t)(rr * HID + d) * HID;
    const float* wpr = Wpr1 + d * HID;
    for (int k = 0; k < HID; k++) { s1 += wp[k] * wmr[k]; s2 += wp[k] * wpr[k]; }
    diag1[rr * HID + d] = s1;
    outrel[rr * HID + d] = s2;
}

// Wb = bf16(Wme1)  (50*4096 elements)
__global__ __launch_bounds__(256) void k_wconv(const float* __restrict__ Wme1,
                                               unsigned short* __restrict__ Wb) {
    int i = blockIdx.x * 256 + threadIdx.x;
    if (i < NUM_REL * HID * HID) Wb[i] = f2bf(Wme1[i]);
}

// ============================================================
// layer 0: transpose Wme0 chunk (+diag0 folded) -> P (bf16)
// ============================================================

__global__ __launch_bounds__(256) void k_transpose(const float* __restrict__ W,
                                                   const float* __restrict__ diag0,
                                                   unsigned short* __restrict__ P,
                                                   int r0, int RS) {
    __shared__ float tile[64][65];
    __shared__ float dg[64];
    int rl = blockIdx.x;
    int rr = r0 + rl;
    int e0 = blockIdx.y * 64;
    int tid = threadIdx.x;
    if (tid < 64) dg[tid] = diag0[rr * HID + tid];
    for (int i = tid; i < 4096; i += 256) {
        int dd = i >> 6, xx = i & 63;
        int e = e0 + xx;
        tile[dd][xx] = (e < NUM_ENT) ? W[(size_t)(rr * HID + dd) * NUM_ENT + e] : 0.f;
    }
    __syncthreads();
    for (int i = tid; i < 4096; i += 256) {
        int ee = i >> 6, dd = i & 63;
        int e = e0 + ee;
        if (e < NUM_ENT)
            P[(size_t)e * RS + (size_t)rl * 64 + dd] = f2bf(tile[dd][ee] + dg[dd]);
    }
}

// ============================================================
// layer 1: B[e, rl*64+d] = bf16( A[e,:].Wme1_rr[d,:] + diag1[rr,d] )  (MFMA)
// grid (net, nsplit); block = 4 waves, wave w covers rows e0+w*16..+15
// ============================================================

__global__ __launch_bounds__(256) void k_gemmB(const unsigned short* __restrict__ Abf,
                                               const unsigned short* __restrict__ Wb,
                                               const float* __restrict__ diag1,
                                               unsigned short* __restrict__ B,
                                               int r0, int grels, int RS, int percut) {
    int e0 = blockIdx.x * 64;
    int rl0 = blockIdx.y * percut;
    int rl1 = rl0 + percut;
    if (rl1 > grels) rl1 = grels;
    int w = (int)threadIdx.x >> 6;
    int lane = (int)threadIdx.x & 63;
    int lrow = lane & 15;
    int hi = lane >> 4;
    int lk8 = hi * 8;
    int row = e0 + w * 16 + lrow;
    int rowc = row < NUM_ENT ? row : NUM_ENT - 1;
    short8 a0 = ld8(Abf + (size_t)rowc * HID + lk8);
    short8 a1 = ld8(Abf + (size_t)rowc * HID + 32 + lk8);

    for (int rl = rl0; rl < rl1; ++rl) {
        const unsigned short* wb = Wb + (size_t)(r0 + rl) * 4096;
        f32x4 acc[4] = {};
#pragma unroll
        for (int tt = 0; tt < 4; ++tt) {
            const unsigned short* wd = wb + (tt * 16 + lrow) * 64;
            short8 b0 = ld8(wd + lk8);
            short8 b1 = ld8(wd + 32 + lk8);
            acc[tt] = __builtin_amdgcn_mfma_f32_16x16x32_bf16(a0, b0, acc[tt], 0, 0, 0);
            acc[tt] = __builtin_amdgcn_mfma_f32_16x16x32_bf16(a1, b1, acc[tt], 0, 0, 0);
        }
#pragma unroll
        for (int tt = 0; tt < 4; ++tt) {
            float dgv = diag1[(r0 + rl) * HID + tt * 16 + lrow];
#pragma unroll
            for (int q = 0; q < 4; ++q) {
                int eo = e0 + w * 16 + hi * 4 + q;
                if (eo < NUM_ENT)
                    B[(size_t)eo * RS + rl * 64 + tt * 16 + lrow] = f2bf(acc[tt][q] + dgv);
            }
        }
    }
}

// ============================================================
// tail-owned gather-accumulate: target[e,:] += sum_j table[off_j + :]
// ============================================================

__global__ __launch_bounds__(256) void k_scatter(const unsigned short* __restrict__ table,
                                                 const int* __restrict__ toff,
                                                 const unsigned* __restrict__ bucket2,
                                                 float* __restrict__ target,
                                                 unsigned short* __restrict__ Abf,
                                                 int applyAct, int writeA) {
    int e = __builtin_amdgcn_readfirstlane(blockIdx.x * 4 + (threadIdx.x >> 6));
    int d = threadIdx.x & 63;
    if (e >= NUM_ENT) return;
    int j0 = toff[e], j1 = toff[e + 1];
    float acc = 0.f, acc2 = 0.f, acc3 = 0.f, acc4 = 0.f;
    int j = j0;
    for (; j + 4 <= j1; j += 4) {
        unsigned o0 = bucket2[j], o1 = bucket2[j + 1];
        unsigned o2 = bucket2[j + 2], o3 = bucket2[j + 3];
        acc  += bf2f(table[o0 + d]);
        acc2 += bf2f(table[o1 + d]);
        acc3 += bf2f(table[o2 + d]);
        acc4 += bf2f(table[o3 + d]);
    }
    for (; j < j1; ++j) acc += bf2f(table[bucket2[j] + d]);
    acc += acc2 + acc3 + acc4;
    float v = target[e * HID + d] + acc;
    if (applyAct) v = (v >= 0.f) ? v : 0.01f * v;
    if (writeA) Abf[e * HID + d] = f2bf(v);
    target[e * HID + d] = v;
}

// out[e,d] = sum_k A[e,k] * Wres1[d,k]   (fp32 base for layer-1 accumulation)
__global__ void k_init_u1(const float* __restrict__ A, const float* __restrict__ Wres1,
                          float* __restrict__ out) {
    __shared__ float W[HID][HID + 1];
    int tid = threadIdx.x;
    for (int i = tid; i < HID * HID; i += 256) W[i >> 6][i & 63] = Wres1[i];
    __syncthreads();
    int g = blockIdx.x * 256 + tid;
    int e = g >> 6, d = g & 63;
    if (e >= NUM_ENT) return;
    const float4* arow = (const float4*)(A + (size_t)e * HID);
    float acc = 0.0f;
#pragma unroll
    for (int k4 = 0; k4 < 16; k4++) {
        float4 a = arow[k4];
        acc = fmaf(a.x, W[d][k4 * 4 + 0], acc);
        acc = fmaf(a.y, W[d][k4 * 4 + 1], acc);
        acc = fmaf(a.z, W[d][k4 * 4 + 2], acc);
        acc = fmaf(a.w, W[d][k4 * 4 + 3], acc);
    }
    out[g] = acc;
}

// ============================================================
// fallback path (round-1 atomic kernels) — used only if ws too small
// ============================================================

__global__ void k_hist(const int* __restrict__ r, int* __restrict__ hist) {
    __shared__ int lh[NUM_REL];
    int tid = threadIdx.x;
    if (tid < NUM_REL) lh[tid] = 0;
    __syncthreads();
    int i = blockIdx.x * blockDim.x + tid;
    if (i < NTRIP) atomicAdd(&lh[r[i]], 1);
    __syncthreads();
    if (tid < NUM_REL && lh[tid] > 0) atomicAdd(&hist[tid], lh[tid]);
}

__global__ void k_scan_small(const int* __restrict__ hist, int* __restrict__ off,
                             int* __restrict__ cur) {
    if (threadIdx.x == 0 && blockIdx.x == 0) {
        int s = 0;
        for (int i = 0; i < NUM_REL; i++) { off[i] = s; cur[i] = s; s += hist[i]; }
        off[NUM_REL] = s;
    }
}

__global__ void k_bucket(const int* __restrict__ h, const int* __restrict__ r,
                         const int* __restrict__ t, int* __restrict__ cur,
                         int2* __restrict__ bucket) {
    __shared__ int lcnt[NUM_REL];
    __shared__ int lbase[NUM_REL];
    int tid = threadIdx.x;
    if (tid < NUM_REL) lcnt[tid] = 0;
    __syncthreads();
    int i = blockIdx.x * blockDim.x + tid;
    int rr = -1, lpos = 0;
    if (i < NTRIP) { rr = r[i]; lpos = atomicAdd(&lcnt[rr], 1); }
    __syncthreads();
    if (tid < NUM_REL && lcnt[tid] > 0) lbase[tid] = atomicAdd(&cur[tid], lcnt[tid]);
    __syncthreads();
    if (i < NTRIP) bucket[lbase[rr] + lpos] = make_int2(h[i], t[i]);
}

__global__ void k_l0(const float* __restrict__ Wme0, const float* __restrict__ Wmr0,
                     const int* __restrict__ off, const int2* __restrict__ bucket,
                     float* __restrict__ U0) {
    __shared__ float row[NUM_ENT];
    int rr = blockIdx.x >> 6;
    int d  = blockIdx.x & 63;
    const float4* src4 = (const float4*)(Wme0 + (size_t)(rr * HID + d) * NUM_ENT);
    float4* row4 = (float4*)row;
    for (int i = threadIdx.x; i < NUM_ENT / 4; i += blockDim.x) row4[i] = src4[i];
    __syncthreads();
    float wd0 = Wmr0[(size_t)(rr * HID + d) * NUM_REL + rr];
    int b0 = off[rr], b1 = off[rr + 1];
    for (int i = b0 + threadIdx.x; i < b1; i += blockDim.x) {
        int2 ht = bucket[i];
        atomicAdd(&U0[(size_t)ht.y * HID + d], row[ht.x] + wd0);
    }
}

__global__ void k_lrelu(float* __restrict__ x, int n) {
    int i = blockIdx.x * blockDim.x + threadIdx.x;
    if (i < n) { float v = x[i]; x[i] = v >= 0.0f ? v : 0.01f * v; }
}

#define L1_CHUNKS 16
__global__ void k_l1(const float* __restrict__ A, const float* __restrict__ Wme1,
                     const int* __restrict__ off, const int2* __restrict__ bucket,
                     const float* __restrict__ diag1, float* __restrict__ out) {
    int rr = blockIdx.x / L1_CHUNKS;
    int chunk = blockIdx.x % L1_CHUNKS;
    int b0 = off[rr], b1 = off[rr + 1];
    for (int i = b0 + chunk * 256 + (int)threadIdx.x; i < b1; i += L1_CHUNKS * 256) {
        int2 ht = bucket[i];
        const float4* arow = (const float4*)(A + (size_t)ht.x * HID);
        float4 a[16];
#pragma unroll
        for (int j = 0; j < 16; j++) a[j] = arow[j];
        float* op = out + (size_t)ht.y * HID;
#pragma unroll 4
        for (int d = 0; d < HID; d++) {
            const float4* m4 = (const float4*)(Wme1 + (size_t)(rr * HID + d) * HID);
            float acc = diag1[rr * HID + d];
#pragma unroll
            for (int k = 0; k < 16; k++) {
                float4 m = m4[k];
                acc = fmaf(a[k].x, m.x, acc);
                acc = fmaf(a[k].y, m.y, acc);
                acc = fmaf(a[k].z, m.z, acc);
                acc = fmaf(a[k].w, m.w, acc);
            }
            atomicAdd(op + d, acc);
        }
    }
}

// ============================================================
// launch
// ============================================================

static inline size_t align_up(size_t x, size_t a) { return (x + a - 1) & ~(a - 1); }

extern "C" void kernel_launch(void* const* d_in, const int* in_sizes, int n_in,
                              void* d_out, int out_size, void* d_ws, size_t ws_size,
                              hipStream_t stream) {
    const float* Wres0 = (const float*)d_in[0];
    const float* Wme0  = (const float*)d_in[1];
    const float* Wmr0  = (const float*)d_in[2];
    const float* Wpr0  = (const float*)d_in[3];
    const float* Wres1 = (const float*)d_in[4];
    const float* Wme1  = (const float*)d_in[5];
    const float* Wmr1  = (const float*)d_in[6];
    const float* Wpr1  = (const float*)d_in[7];
    const int* h = (const int*)d_in[8];
    const int* r = (const int*)d_in[9];
    const int* t = (const int*)d_in[10];
    float* out = (float*)d_out;  // [640000 ent | 3200 rel]

    char* ws = (char*)d_ws;
    const int nbt = (NTRIP + 255) / 256;       // 1954
    const int net = (NUM_ENT + 63) / 64;       // 157

    // pick GR = 50 (1 group) if it fits, else 25 (2 groups), else fallback
    int GR = 0, ngroups = 0;
    size_t oTab = 0, oB2 = 0, oToff = 0, oBins = 0, oU0 = 0, oAbf = 0, oD0 = 0,
           oD1 = 0, oWb = 0;
    for (int gr = NUM_REL; gr >= 25; gr -= 25) {
        int ng = NUM_REL / gr;
        size_t p = 0;
        size_t Tb_  = p; p += align_up((size_t)gr * 64 * NUM_ENT * 2, 256);
        size_t B2_  = p; p += align_up((size_t)NTRIP * 4, 256);
        size_t Tf_  = p; p += align_up(((size_t)ng * NUM_ENT + 1) * 4, 256);
        size_t Bn_  = p; p += align_up((size_t)ng * NUM_ENT * 4, 256);
        size_t U0_  = p; p += align_up((size_t)NUM_ENT * HID * 4, 256);
        size_t Ab_  = p; p += align_up((size_t)NUM_ENT * HID * 2, 256);
        size_t D0_  = p; p += align_up((size_t)NUM_REL * HID * 4, 256);
        size_t D1_  = p; p += align_up((size_t)NUM_REL * HID * 4, 256);
        size_t Wb_  = p; p += align_up((size_t)NUM_REL * HID * HID * 2, 256);
        if (p <= ws_size) {
            GR = gr; ngroups = ng;
            oTab = Tb_; oB2 = B2_; oToff = Tf_; oBins = Bn_; oU0 = U0_; oAbf = Ab_;
            oD0 = D0_; oD1 = D1_; oWb = Wb_;
            break;
        }
    }

    if (GR >= 25) {
        unsigned short* Tab   = (unsigned short*)(ws + oTab);   // P then B
        unsigned* bucket2     = (unsigned*)(ws + oB2);
        int*      toff        = (int*)(ws + oToff);
        int*      bins        = (int*)(ws + oBins);
        float*    U0          = (float*)(ws + oU0);
        unsigned short* Abf   = (unsigned short*)(ws + oAbf);
        float*    diag0       = (float*)(ws + oD0);
        float*    diag1       = (float*)(ws + oD1);
        unsigned short* Wb    = (unsigned short*)(ws + oWb);
        int nbins = ngroups * NUM_ENT;
        int RS = GR * 64;
        int nsplit = 5;
        int percut = (GR + nsplit - 1) / nsplit;

        hipMemsetAsync(bins, 0, (size_t)nbins * 4, stream);
        k_thist<<<nbt, 256, 0, stream>>>(r, t, bins, GR);
        k_scan<<<1, 1024, 0, stream>>>(bins, toff, nbins);
        k_tscatter<<<nbt, 256, 0, stream>>>(h, r, t, bins, bucket2, GR, RS);

        k_diag0<<<(NUM_REL * HID + 255) / 256, 256, 0, stream>>>(Wmr0, diag0);
        k_init_u0<<<net, 256, 0, stream>>>(Wres0, U0);
        k_rel<<<NUM_REL, HID, 0, stream>>>(Wpr0, Wmr1, Wpr1, diag1, out + NUM_ENT * HID);
        k_wconv<<<(NUM_REL * HID * HID + 255) / 256, 256, 0, stream>>>(Wme1, Wb);

        // ---- layer 0 ----
        for (int g = 0; g < ngroups; ++g) {
            int last = (g == ngroups - 1) ? 1 : 0;
            k_transpose<<<dim3(GR, net), 256, 0, stream>>>(Wme0, diag0, Tab, g * GR, RS);
            k_scatter<<<(NUM_ENT + 3) / 4, 256, 0, stream>>>(
                Tab, toff + (size_t)g * NUM_ENT, bucket2, U0, Abf, last, last);
        }
        // U0 = A (fp32, activated); Abf = A (bf16)

        k_init_u1<<<(NUM_ENT * HID) / 256, 256, 0, stream>>>(U0, Wres1, out);

        // ---- layer 1 ----
        for (int g = 0; g < ngroups; ++g) {
            int last = (g == ngroups - 1) ? 1 : 0;
            k_gemmB<<<dim3(net, nsplit), 256, 0, stream>>>(Abf, Wb, diag1, Tab,
                                                           g * GR, GR, RS, percut);
            k_scatter<<<(NUM_ENT + 3) / 4, 256, 0, stream>>>(
                Tab, toff + (size_t)g * NUM_ENT, bucket2, out, Abf, last, 0);
        }
        return;
    }

    // ---------- fallback: round-1 atomic path ----------
    {
        int2*  bucket = (int2*)ws;                    // 4,000,000 B
        float* U0     = (float*)(ws + 4000000);       // 2,560,000 B
        float* diag1  = (float*)(ws + 6560000);       // 12,800 B
        int*   hist   = (int*)(ws + 6572800);
        int*   off    = (int*)(ws + 6573056);
        int*   cur    = (int*)(ws + 6573312);

        hipMemsetAsync(hist, 0, NUM_REL * sizeof(int), stream);
        k_hist<<<nbt, 256, 0, stream>>>(r, hist);
        k_scan_small<<<1, 64, 0, stream>>>(hist, off, cur);
        k_bucket<<<nbt, 256, 0, stream>>>(h, r, t, cur, bucket);

        k_init_u0<<<net, 256, 0, stream>>>(Wres0, U0);
        k_l0<<<NUM_REL * HID, 256, 0, stream>>>(Wme0, Wmr0, off, bucket, U0);
        k_lrelu<<<(NUM_ENT * HID + 255) / 256, 256, 0, stream>>>(U0, NUM_ENT * HID);

        k_rel<<<NUM_REL, HID, 0, stream>>>(Wpr0, Wmr1, Wpr1, diag1, out + NUM_ENT * HID);
        k_init_u1<<<(NUM_ENT * HID) / 256, 256, 0, stream>>>(U0, Wres1, out);
        k_l1<<<NUM_REL * L1_CHUNKS, 256, 0, stream>>>(U0, Wme1, off, bucket, diag1, out);
        k_lrelu<<<(NUM_ENT * HID + 255) / 256, 256, 0, stream>>>(out, NUM_ENT * HID);
    }
}

// Round 6
// 239.932 us; speedup vs baseline: 1.7199x; 1.0200x over previous
//
#include <hip/hip_runtime.h>

#define NUM_ENT 10000
#define NUM_REL 50
#define HID 64
#define NTRIP 500000

typedef __attribute__((ext_vector_type(8))) short short8;
typedef __attribute__((ext_vector_type(4))) float f32x4;

// bf16 helpers (RNE)
static __device__ __forceinline__ unsigned short f2bf(float x) {
    unsigned u = __float_as_uint(x);
    return (unsigned short)((u + 0x7FFFu + ((u >> 16) & 1u)) >> 16);
}
static __device__ __forceinline__ float bf2f(unsigned short b) {
    return __uint_as_float((unsigned)b << 16);
}
static __device__ __forceinline__ short8 ld8(const unsigned short* p) {
    return *(const short8*)p;
}

// ============================================================
// bucketing: bins keyed (r/GR)*NUM_ENT + t ; bucket stores element offset
// off = h*RS + (r%GR)*64
// ============================================================

__global__ __launch_bounds__(256) void k_zero(int* __restrict__ p, int n) {
    int i = blockIdx.x * 256 + threadIdx.x;
    if (i < n) p[i] = 0;
}

__global__ __launch_bounds__(256) void k_thist(const int* __restrict__ r,
                                               const int* __restrict__ t,
                                               int* __restrict__ bins, int gsz) {
    int i = blockIdx.x * 256 + threadIdx.x;
    if (i < NTRIP) atomicAdd(&bins[(r[i] / gsz) * NUM_ENT + t[i]], 1);
}

__global__ __launch_bounds__(1024) void k_scan(int* __restrict__ bins,
                                               int* __restrict__ toff, int nbins) {
    __shared__ int wsum[16];
    int tid = threadIdx.x, lane = tid & 63, w = tid >> 6;
    int running = 0;
    for (int base = 0; base < nbins; base += 1024) {
        int i = base + tid;
        int s = (i < nbins) ? bins[i] : 0;
        int v = s;
        for (int off = 1; off < 64; off <<= 1) {
            int u = __shfl_up(v, off);
            if (lane >= off) v += u;
        }
        if (lane == 63) wsum[w] = v;
        __syncthreads();
        int woff = 0, tot = 0;
#pragma unroll
        for (int k = 0; k < 16; ++k) {
            int x = wsum[k];
            woff += (k < w) ? x : 0;
            tot += x;
        }
        int excl = running + woff + (v - s);
        if (i < nbins) { toff[i] = excl; bins[i] = excl; }
        running += tot;
        __syncthreads();
    }
    if (tid == 0) toff[nbins] = running;
}

__global__ __launch_bounds__(256) void k_tscatter(const int* __restrict__ h,
                                                  const int* __restrict__ r,
                                                  const int* __restrict__ t,
                                                  int* __restrict__ cur,
                                                  unsigned* __restrict__ bucket2,
                                                  int gsz, int RS) {
    int i = blockIdx.x * 256 + threadIdx.x;
    if (i < NTRIP) {
        int rr = r[i];
        int g = rr / gsz;
        int pos = atomicAdd(&cur[g * NUM_ENT + t[i]], 1);
        bucket2[pos] = (unsigned)h[i] * (unsigned)RS + (unsigned)(rr - g * gsz) * 64u;
    }
}

// ============================================================
// small prep kernels
// ============================================================

__global__ void k_diag0(const float* __restrict__ Wmr0, float* __restrict__ diag0) {
    int i = blockIdx.x * 256 + threadIdx.x;
    if (i < NUM_REL * HID) diag0[i] = Wmr0[(size_t)i * NUM_REL + (i >> 6)];
}

// U0[e,d] = Wres0[d,e]
__global__ void k_init_u0(const float* __restrict__ Wres0, float* __restrict__ U0) {
    __shared__ float tile[64][65];
    int e0 = blockIdx.x * 64;
    for (int i = threadIdx.x; i < 64 * 64; i += 256) {
        int dd = i >> 6, xx = i & 63;
        if (e0 + xx < NUM_ENT) tile[xx][dd] = Wres0[dd * NUM_ENT + e0 + xx];
    }
    __syncthreads();
    for (int i = threadIdx.x; i < 64 * 64; i += 256) {
        int ee = i >> 6, dd = i & 63;
        if (e0 + ee < NUM_ENT) U0[(e0 + ee) * HID + dd] = tile[ee][dd];
    }
}

// diag1[r,d]; outrel[r,d]
__global__ void k_rel(const float* __restrict__ Wpr0, const float* __restrict__ Wmr1,
                      const float* __restrict__ Wpr1, float* __restrict__ diag1,
                      float* __restrict__ outrel) {
    __shared__ float wp[HID];
    int rr = blockIdx.x, d = threadIdx.x;
    wp[d] = Wpr0[d * NUM_REL + rr];
    __syncthreads();
    float s1 = 0.0f, s2 = 0.0f;
    const float* wmr = Wmr1 + (size_t)(rr * HID + d) * HID;
    const float* wpr = Wpr1 + d * HID;
    for (int k = 0; k < HID; k++) { s1 += wp[k] * wmr[k]; s2 += wp[k] * wpr[k]; }
    diag1[rr * HID + d] = s1;
    outrel[rr * HID + d] = s2;
}

// Wb = bf16(Wme1)
__global__ __launch_bounds__(256) void k_wconv(const float* __restrict__ Wme1,
                                               unsigned short* __restrict__ Wb) {
    int i = blockIdx.x * 256 + threadIdx.x;
    if (i < NUM_REL * HID * HID) Wb[i] = f2bf(Wme1[i]);
}

// ============================================================
// layer 0: transpose Wme0 chunk (+diag0 folded) -> P (bf16), vectorized
// ============================================================

__global__ __launch_bounds__(256) void k_transpose(const float* __restrict__ W,
                                                   const float* __restrict__ diag0,
                                                   unsigned short* __restrict__ P,
                                                   int r0, int RS) {
    __shared__ float tile[64][65];
    __shared__ float dg[64];
    int rl = blockIdx.x;
    int rr = r0 + rl;
    int e0 = blockIdx.y * 64;
    int tid = threadIdx.x;
    if (tid < 64) dg[tid] = diag0[rr * HID + tid];
    const float* Wbase = W + (size_t)(rr * HID) * NUM_ENT + e0;
    bool full = (e0 + 64 <= NUM_ENT);
    if (full) {
#pragma unroll
        for (int it = 0; it < 4; ++it) {
            int i2 = tid + it * 256;        // 0..1023 (float4 index)
            int dd = i2 >> 4;
            int x4 = (i2 & 15) * 4;
            float4 v = *(const float4*)(Wbase + (size_t)dd * NUM_ENT + x4);
            tile[dd][x4 + 0] = v.x; tile[dd][x4 + 1] = v.y;
            tile[dd][x4 + 2] = v.z; tile[dd][x4 + 3] = v.w;
        }
    } else {
        for (int i = tid; i < 4096; i += 256) {
            int dd = i >> 6, xx = i & 63;
            tile[dd][xx] = (e0 + xx < NUM_ENT) ? Wbase[(size_t)dd * NUM_ENT + xx] : 0.f;
        }
    }
    __syncthreads();
    if (full) {
#pragma unroll
        for (int it = 0; it < 2; ++it) {
            int idx = tid + it * 256;       // 0..511 (ushort8 index)
            int ee = idx >> 3;
            int d0 = (idx & 7) * 8;
            unsigned short pk[8];
#pragma unroll
            for (int k = 0; k < 8; ++k) pk[k] = f2bf(tile[d0 + k][ee] + dg[d0 + k]);
            *(short8*)&P[(size_t)(e0 + ee) * RS + (size_t)rl * 64 + d0] = *(const short8*)pk;
        }
    } else {
        for (int i = tid; i < 4096; i += 256) {
            int ee = i >> 6, dd = i & 63;
            int e = e0 + ee;
            if (e < NUM_ENT)
                P[(size_t)e * RS + (size_t)rl * 64 + dd] = f2bf(tile[dd][ee] + dg[dd]);
        }
    }
}

// ============================================================
// layer 1: B[e, rl*64+d] = bf16( A[e,:].Wme1_rr[d,:] + diag1[rr,d] )  (MFMA)
// ============================================================

__global__ __launch_bounds__(256) void k_gemmB(const unsigned short* __restrict__ Abf,
                                               const unsigned short* __restrict__ Wb,
                                               const float* __restrict__ diag1,
                                               unsigned short* __restrict__ B,
                                               int r0, int grels, int RS, int percut) {
    int e0 = blockIdx.x * 64;
    int rl0 = blockIdx.y * percut;
    int rl1 = rl0 + percut;
    if (rl1 > grels) rl1 = grels;
    int w = (int)threadIdx.x >> 6;
    int lane = (int)threadIdx.x & 63;
    int lrow = lane & 15;
    int hi = lane >> 4;
    int lk8 = hi * 8;
    int row = e0 + w * 16 + lrow;
    int rowc = row < NUM_ENT ? row : NUM_ENT - 1;
    short8 a0 = ld8(Abf + (size_t)rowc * HID + lk8);
    short8 a1 = ld8(Abf + (size_t)rowc * HID + 32 + lk8);

    for (int rl = rl0; rl < rl1; ++rl) {
        const unsigned short* wb = Wb + (size_t)(r0 + rl) * 4096;
        f32x4 acc[4] = {};
#pragma unroll
        for (int tt = 0; tt < 4; ++tt) {
            const unsigned short* wd = wb + (tt * 16 + lrow) * 64;
            short8 b0 = ld8(wd + lk8);
            short8 b1 = ld8(wd + 32 + lk8);
            acc[tt] = __builtin_amdgcn_mfma_f32_16x16x32_bf16(a0, b0, acc[tt], 0, 0, 0);
            acc[tt] = __builtin_amdgcn_mfma_f32_16x16x32_bf16(a1, b1, acc[tt], 0, 0, 0);
        }
#pragma unroll
        for (int tt = 0; tt < 4; ++tt) {
            float dgv = diag1[(r0 + rl) * HID + tt * 16 + lrow];
#pragma unroll
            for (int q = 0; q < 4; ++q) {
                int eo = e0 + w * 16 + hi * 4 + q;
                if (eo < NUM_ENT)
                    B[(size_t)eo * RS + rl * 64 + tt * 16 + lrow] = f2bf(acc[tt][q] + dgv);
            }
        }
    }
}

// ============================================================
// tail-owned gather-accumulate: target[e,:] += sum_j table[off_j + :]
// quarter-wave gather: 16 lanes x uint2 = one 128B row; 4 rows/wave-iter
// ============================================================

__global__ __launch_bounds__(256) void k_scatter(const unsigned short* __restrict__ table,
                                                 const int* __restrict__ toff,
                                                 const unsigned* __restrict__ bucket2,
                                                 float* __restrict__ target,
                                                 unsigned short* __restrict__ Abf,
                                                 int applyAct, int writeA) {
    int e = __builtin_amdgcn_readfirstlane(blockIdx.x * 4 + (threadIdx.x >> 6));
    if (e >= NUM_ENT) return;
    int lane = threadIdx.x & 63;
    int q4 = lane >> 4;          // quarter 0..3
    int sl = lane & 15;          // covers d = 4sl .. 4sl+3
    int j0 = toff[e], j1 = toff[e + 1];
    float a0 = 0.f, a1 = 0.f, a2 = 0.f, a3 = 0.f;
    float b0 = 0.f, b1 = 0.f, b2 = 0.f, b3 = 0.f;
    int jj = j0;
    for (; jj + 8 <= j1; jj += 8) {
        unsigned oA = bucket2[jj + q4];
        unsigned oB = bucket2[jj + 4 + q4];
        uint2 vA = *(const uint2*)(table + oA + 4 * sl);
        uint2 vB = *(const uint2*)(table + oB + 4 * sl);
        a0 += bf2f((unsigned short)vA.x); a1 += bf2f((unsigned short)(vA.x >> 16));
        a2 += bf2f((unsigned short)vA.y); a3 += bf2f((unsigned short)(vA.y >> 16));
        b0 += bf2f((unsigned short)vB.x); b1 += bf2f((unsigned short)(vB.x >> 16));
        b2 += bf2f((unsigned short)vB.y); b3 += bf2f((unsigned short)(vB.y >> 16));
    }
    if (jj + 4 <= j1) {
        unsigned oA = bucket2[jj + q4];
        uint2 vA = *(const uint2*)(table + oA + 4 * sl);
        a0 += bf2f((unsigned short)vA.x); a1 += bf2f((unsigned short)(vA.x >> 16));
        a2 += bf2f((unsigned short)vA.y); a3 += bf2f((unsigned short)(vA.y >> 16));
        jj += 4;
    }
    if (q4 == 0) {               // 0..3 leftovers, quarter 0 only
        for (; jj < j1; ++jj) {
            unsigned o = bucket2[jj];
            uint2 v = *(const uint2*)(table + o + 4 * sl);
            b0 += bf2f((unsigned short)v.x); b1 += bf2f((unsigned short)(v.x >> 16));
            b2 += bf2f((unsigned short)v.y); b3 += bf2f((unsigned short)(v.y >> 16));
        }
    }
    a0 += b0; a1 += b1; a2 += b2; a3 += b3;
    a0 += __shfl_xor(a0, 16); a0 += __shfl_xor(a0, 32);
    a1 += __shfl_xor(a1, 16); a1 += __shfl_xor(a1, 32);
    a2 += __shfl_xor(a2, 16); a2 += __shfl_xor(a2, 32);
    a3 += __shfl_xor(a3, 16); a3 += __shfl_xor(a3, 32);
    if (q4 == 0) {
        float4 tv = *(const float4*)(target + (size_t)e * HID + 4 * sl);
        float v0 = tv.x + a0, v1 = tv.y + a1, v2 = tv.z + a2, v3 = tv.w + a3;
        if (applyAct) {
            v0 = (v0 >= 0.f) ? v0 : 0.01f * v0;
            v1 = (v1 >= 0.f) ? v1 : 0.01f * v1;
            v2 = (v2 >= 0.f) ? v2 : 0.01f * v2;
            v3 = (v3 >= 0.f) ? v3 : 0.01f * v3;
        }
        if (writeA) {
            uint2 pk;
            pk.x = (unsigned)f2bf(v0) | ((unsigned)f2bf(v1) << 16);
            pk.y = (unsigned)f2bf(v2) | ((unsigned)f2bf(v3) << 16);
            *(uint2*)&Abf[(size_t)e * HID + 4 * sl] = pk;
        }
        *(float4*)(target + (size_t)e * HID + 4 * sl) = make_float4(v0, v1, v2, v3);
    }
}

// out[e,d] = sum_k A[e,k] * Wres1[d,k]
__global__ void k_init_u1(const float* __restrict__ A, const float* __restrict__ Wres1,
                          float* __restrict__ out) {
    __shared__ float W[HID][HID + 1];
    int tid = threadIdx.x;
    for (int i = tid; i < HID * HID; i += 256) W[i >> 6][i & 63] = Wres1[i];
    __syncthreads();
    int g = blockIdx.x * 256 + tid;
    int e = g >> 6, d = g & 63;
    if (e >= NUM_ENT) return;
    const float4* arow = (const float4*)(A + (size_t)e * HID);
    float acc = 0.0f;
#pragma unroll
    for (int k4 = 0; k4 < 16; k4++) {
        float4 a = arow[k4];
        acc = fmaf(a.x, W[d][k4 * 4 + 0], acc);
        acc = fmaf(a.y, W[d][k4 * 4 + 1], acc);
        acc = fmaf(a.z, W[d][k4 * 4 + 2], acc);
        acc = fmaf(a.w, W[d][k4 * 4 + 3], acc);
    }
    out[g] = acc;
}

// ============================================================
// fallback path (round-1 atomic kernels) — used only if ws too small
// ============================================================

__global__ void k_hist(const int* __restrict__ r, int* __restrict__ hist) {
    __shared__ int lh[NUM_REL];
    int tid = threadIdx.x;
    if (tid < NUM_REL) lh[tid] = 0;
    __syncthreads();
    int i = blockIdx.x * blockDim.x + tid;
    if (i < NTRIP) atomicAdd(&lh[r[i]], 1);
    __syncthreads();
    if (tid < NUM_REL && lh[tid] > 0) atomicAdd(&hist[tid], lh[tid]);
}

__global__ void k_scan_small(const int* __restrict__ hist, int* __restrict__ off,
                             int* __restrict__ cur) {
    if (threadIdx.x == 0 && blockIdx.x == 0) {
        int s = 0;
        for (int i = 0; i < NUM_REL; i++) { off[i] = s; cur[i] = s; s += hist[i]; }
        off[NUM_REL] = s;
    }
}

__global__ void k_bucket(const int* __restrict__ h, const int* __restrict__ r,
                         const int* __restrict__ t, int* __restrict__ cur,
                         int2* __restrict__ bucket) {
    __shared__ int lcnt[NUM_REL];
    __shared__ int lbase[NUM_REL];
    int tid = threadIdx.x;
    if (tid < NUM_REL) lcnt[tid] = 0;
    __syncthreads();
    int i = blockIdx.x * blockDim.x + tid;
    int rr = -1, lpos = 0;
    if (i < NTRIP) { rr = r[i]; lpos = atomicAdd(&lcnt[rr], 1); }
    __syncthreads();
    if (tid < NUM_REL && lcnt[tid] > 0) lbase[tid] = atomicAdd(&cur[tid], lcnt[tid]);
    __syncthreads();
    if (i < NTRIP) bucket[lbase[rr] + lpos] = make_int2(h[i], t[i]);
}

__global__ void k_l0(const float* __restrict__ Wme0, const float* __restrict__ Wmr0,
                     const int* __restrict__ off, const int2* __restrict__ bucket,
                     float* __restrict__ U0) {
    __shared__ float row[NUM_ENT];
    int rr = blockIdx.x >> 6;
    int d  = blockIdx.x & 63;
    const float4* src4 = (const float4*)(Wme0 + (size_t)(rr * HID + d) * NUM_ENT);
    float4* row4 = (float4*)row;
    for (int i = threadIdx.x; i < NUM_ENT / 4; i += blockDim.x) row4[i] = src4[i];
    __syncthreads();
    float wd0 = Wmr0[(size_t)(rr * HID + d) * NUM_REL + rr];
    int b0 = off[rr], b1 = off[rr + 1];
    for (int i = b0 + threadIdx.x; i < b1; i += blockDim.x) {
        int2 ht = bucket[i];
        atomicAdd(&U0[(size_t)ht.y * HID + d], row[ht.x] + wd0);
    }
}

__global__ void k_lrelu(float* __restrict__ x, int n) {
    int i = blockIdx.x * blockDim.x + threadIdx.x;
    if (i < n) { float v = x[i]; x[i] = v >= 0.0f ? v : 0.01f * v; }
}

#define L1_CHUNKS 16
__global__ void k_l1(const float* __restrict__ A, const float* __restrict__ Wme1,
                     const int* __restrict__ off, const int2* __restrict__ bucket,
                     const float* __restrict__ diag1, float* __restrict__ out) {
    int rr = blockIdx.x / L1_CHUNKS;
    int chunk = blockIdx.x % L1_CHUNKS;
    int b0 = off[rr], b1 = off[rr + 1];
    for (int i = b0 + chunk * 256 + (int)threadIdx.x; i < b1; i += L1_CHUNKS * 256) {
        int2 ht = bucket[i];
        const float4* arow = (const float4*)(A + (size_t)ht.x * HID);
        float4 a[16];
#pragma unroll
        for (int j = 0; j < 16; j++) a[j] = arow[j];
        float* op = out + (size_t)ht.y * HID;
#pragma unroll 4
        for (int d = 0; d < HID; d++) {
            const float4* m4 = (const float4*)(Wme1 + (size_t)(rr * HID + d) * HID);
            float acc = diag1[rr * HID + d];
#pragma unroll
            for (int k = 0; k < 16; k++) {
                float4 m = m4[k];
                acc = fmaf(a[k].x, m.x, acc);
                acc = fmaf(a[k].y, m.y, acc);
                acc = fmaf(a[k].z, m.z, acc);
                acc = fmaf(a[k].w, m.w, acc);
            }
            atomicAdd(op + d, acc);
        }
    }
}

// ============================================================
// launch
// ============================================================

static inline size_t align_up(size_t x, size_t a) { return (x + a - 1) & ~(a - 1); }

extern "C" void kernel_launch(void* const* d_in, const int* in_sizes, int n_in,
                              void* d_out, int out_size, void* d_ws, size_t ws_size,
                              hipStream_t stream) {
    const float* Wres0 = (const float*)d_in[0];
    const float* Wme0  = (const float*)d_in[1];
    const float* Wmr0  = (const float*)d_in[2];
    const float* Wpr0  = (const float*)d_in[3];
    const float* Wres1 = (const float*)d_in[4];
    const float* Wme1  = (const float*)d_in[5];
    const float* Wmr1  = (const float*)d_in[6];
    const float* Wpr1  = (const float*)d_in[7];
    const int* h = (const int*)d_in[8];
    const int* r = (const int*)d_in[9];
    const int* t = (const int*)d_in[10];
    float* out = (float*)d_out;  // [640000 ent | 3200 rel]

    char* ws = (char*)d_ws;
    const int nbt = (NTRIP + 255) / 256;       // 1954
    const int net = (NUM_ENT + 63) / 64;       // 157

    // pick GR = 50 (1 group) if it fits, else 25 (2 groups), else fallback
    int GR = 0, ngroups = 0;
    size_t oTab = 0, oB2 = 0, oToff = 0, oBins = 0, oU0 = 0, oAbf = 0, oD0 = 0,
           oD1 = 0, oWb = 0;
    for (int gr = NUM_REL; gr >= 25; gr -= 25) {
        int ng = NUM_REL / gr;
        size_t p = 0;
        size_t Tb_  = p; p += align_up((size_t)gr * 64 * NUM_ENT * 2, 256);
        size_t B2_  = p; p += align_up((size_t)NTRIP * 4, 256);
        size_t Tf_  = p; p += align_up(((size_t)ng * NUM_ENT + 1) * 4, 256);
        size_t Bn_  = p; p += align_up((size_t)ng * NUM_ENT * 4, 256);
        size_t U0_  = p; p += align_up((size_t)NUM_ENT * HID * 4, 256);
        size_t Ab_  = p; p += align_up((size_t)NUM_ENT * HID * 2, 256);
        size_t D0_  = p; p += align_up((size_t)NUM_REL * HID * 4, 256);
        size_t D1_  = p; p += align_up((size_t)NUM_REL * HID * 4, 256);
        size_t Wb_  = p; p += align_up((size_t)NUM_REL * HID * HID * 2, 256);
        if (p <= ws_size) {
            GR = gr; ngroups = ng;
            oTab = Tb_; oB2 = B2_; oToff = Tf_; oBins = Bn_; oU0 = U0_; oAbf = Ab_;
            oD0 = D0_; oD1 = D1_; oWb = Wb_;
            break;
        }
    }

    if (GR >= 25) {
        unsigned short* Tab   = (unsigned short*)(ws + oTab);   // P then B
        unsigned* bucket2     = (unsigned*)(ws + oB2);
        int*      toff        = (int*)(ws + oToff);
        int*      bins        = (int*)(ws + oBins);
        float*    U0          = (float*)(ws + oU0);
        unsigned short* Abf   = (unsigned short*)(ws + oAbf);
        float*    diag0       = (float*)(ws + oD0);
        float*    diag1      = (float*)(ws + oD1);
        unsigned short* Wb    = (unsigned short*)(ws + oWb);
        int nbins = ngroups * NUM_ENT;
        int RS = GR * 64;
        int nsplit = 5;
        int percut = (GR + nsplit - 1) / nsplit;

        k_zero<<<(nbins + 255) / 256, 256, 0, stream>>>(bins, nbins);
        k_thist<<<nbt, 256, 0, stream>>>(r, t, bins, GR);
        k_scan<<<1, 1024, 0, stream>>>(bins, toff, nbins);
        k_tscatter<<<nbt, 256, 0, stream>>>(h, r, t, bins, bucket2, GR, RS);

        k_diag0<<<(NUM_REL * HID + 255) / 256, 256, 0, stream>>>(Wmr0, diag0);
        k_init_u0<<<net, 256, 0, stream>>>(Wres0, U0);
        k_rel<<<NUM_REL, HID, 0, stream>>>(Wpr0, Wmr1, Wpr1, diag1, out + NUM_ENT * HID);
        k_wconv<<<(NUM_REL * HID * HID + 255) / 256, 256, 0, stream>>>(Wme1, Wb);

        // ---- layer 0 ----
        for (int g = 0; g < ngroups; ++g) {
            int last = (g == ngroups - 1) ? 1 : 0;
            k_transpose<<<dim3(GR, net), 256, 0, stream>>>(Wme0, diag0, Tab, g * GR, RS);
            k_scatter<<<(NUM_ENT + 3) / 4, 256, 0, stream>>>(
                Tab, toff + (size_t)g * NUM_ENT, bucket2, U0, Abf, last, last);
        }
        // U0 = A (fp32, activated); Abf = A (bf16)

        k_init_u1<<<(NUM_ENT * HID) / 256, 256, 0, stream>>>(U0, Wres1, out);

        // ---- layer 1 ----
        for (int g = 0; g < ngroups; ++g) {
            int last = (g == ngroups - 1) ? 1 : 0;
            k_gemmB<<<dim3(net, nsplit), 256, 0, stream>>>(Abf, Wb, diag1, Tab,
                                                           g * GR, GR, RS, percut);
            k_scatter<<<(NUM_ENT + 3) / 4, 256, 0, stream>>>(
                Tab, toff + (size_t)g * NUM_ENT, bucket2, out, Abf, last, 0);
        }
        return;
    }

    // ---------- fallback: round-1 atomic path ----------
    {
        int2*  bucket = (int2*)ws;                    // 4,000,000 B
        float* U0     = (float*)(ws + 4000000);       // 2,560,000 B
        float* diag1  = (float*)(ws + 6560000);       // 12,800 B
        int*   hist   = (int*)(ws + 6572800);
        int*   off    = (int*)(ws + 6573056);
        int*   cur    = (int*)(ws + 6573312);

        hipMemsetAsync(hist, 0, NUM_REL * sizeof(int), stream);
        k_hist<<<nbt, 256, 0, stream>>>(r, hist);
        k_scan_small<<<1, 64, 0, stream>>>(hist, off, cur);
        k_bucket<<<nbt, 256, 0, stream>>>(h, r, t, cur, bucket);

        k_init_u0<<<net, 256, 0, stream>>>(Wres0, U0);
        k_l0<<<NUM_REL * HID, 256, 0, stream>>>(Wme0, Wmr0, off, bucket, U0);
        k_lrelu<<<(NUM_ENT * HID + 255) / 256, 256, 0, stream>>>(U0, NUM_ENT * HID);

        k_rel<<<NUM_REL, HID, 0, stream>>>(Wpr0, Wmr1, Wpr1, diag1, out + NUM_ENT * HID);
        k_init_u1<<<(NUM_ENT * HID) / 256, 256, 0, stream>>>(U0, Wres1, out);
        k_l1<<<NUM_REL * L1_CHUNKS, 256, 0, stream>>>(U0, Wme1, off, bucket, diag1, out);
        k_lrelu<<<(NUM_ENT * HID + 255) / 256, 256, 0, stream>>>(out, NUM_ENT * HID);
    }
}

// Round 7
// 194.215 us; speedup vs baseline: 2.1247x; 1.2354x over previous
//
#include <hip/hip_runtime.h>

#define NUM_ENT 10000
#define NUM_REL 50
#define HID 64
#define NTRIP 500000
#define NSLOT 51            // 50 relations + residual slot
#define ETILE 128

typedef __attribute__((ext_vector_type(8))) short short8;
typedef __attribute__((ext_vector_type(4))) float f32x4;

// bf16 helpers (RNE)
static __device__ __forceinline__ unsigned short f2bf(float x) {
    unsigned u = __float_as_uint(x);
    return (unsigned short)((u + 0x7FFFu + ((u >> 16) & 1u)) >> 16);
}
static __device__ __forceinline__ float bf2f(unsigned short b) {
    return __uint_as_float((unsigned)b << 16);
}
static __device__ __forceinline__ short8 ld8(const unsigned short* p) {
    return *(const short8*)p;
}

// ============================================================
// bucketing: one atomic pass (rank+count), scan, non-atomic fill
// ============================================================

__global__ __launch_bounds__(256) void k_zero(int* __restrict__ p, int n) {
    int i = blockIdx.x * 256 + threadIdx.x;
    if (i < n) p[i] = 0;
}

__global__ __launch_bounds__(256) void k_rank(const int* __restrict__ t,
                                              int* __restrict__ bins,
                                              int* __restrict__ rank) {
    int i = blockIdx.x * 256 + threadIdx.x;
    if (i < NTRIP) rank[i] = atomicAdd(&bins[t[i]], 1);
}

__global__ __launch_bounds__(1024) void k_scan(const int* __restrict__ bins,
                                               int* __restrict__ toff, int nbins) {
    __shared__ int wsum[16];
    int tid = threadIdx.x, lane = tid & 63, w = tid >> 6;
    int running = 0;
    for (int base = 0; base < nbins; base += 1024) {
        int i = base + tid;
        int s = (i < nbins) ? bins[i] : 0;
        int v = s;
        for (int off = 1; off < 64; off <<= 1) {
            int u = __shfl_up(v, off);
            if (lane >= off) v += u;
        }
        if (lane == 63) wsum[w] = v;
        __syncthreads();
        int woff = 0, tot = 0;
#pragma unroll
        for (int k = 0; k < 16; ++k) {
            int x = wsum[k];
            woff += (k < w) ? x : 0;
            tot += x;
        }
        int excl = running + woff + (v - s);
        if (i < nbins) toff[i] = excl;
        running += tot;
        __syncthreads();
    }
    if (tid == 0) toff[nbins] = running;
}

__global__ __launch_bounds__(256) void k_fill(const int* __restrict__ h,
                                              const int* __restrict__ r,
                                              const int* __restrict__ t,
                                              const int* __restrict__ rank,
                                              const int* __restrict__ toff,
                                              unsigned* __restrict__ bucket2, int RS) {
    int i = blockIdx.x * 256 + threadIdx.x;
    if (i < NTRIP)
        bucket2[toff[t[i]] + rank[i]] =
            (unsigned)h[i] * (unsigned)RS + (unsigned)r[i] * 64u;
}

// ============================================================
// small prep kernels
// ============================================================

// diag0[s*64+d] = Wmr0[(s*64+d)*50 + s] for s<50, 0 for slot 50
__global__ void k_diag0(const float* __restrict__ Wmr0, float* __restrict__ diag0) {
    int i = blockIdx.x * 256 + threadIdx.x;
    if (i < NSLOT * HID)
        diag0[i] = (i < NUM_REL * HID) ? Wmr0[(size_t)i * NUM_REL + (i >> 6)] : 0.f;
}

// diag1[r,d]; outrel[r,d]  (r<50)
__global__ void k_rel(const float* __restrict__ Wpr0, const float* __restrict__ Wmr1,
                      const float* __restrict__ Wpr1, float* __restrict__ diag1,
                      float* __restrict__ outrel) {
    __shared__ float wp[HID];
    int rr = blockIdx.x, d = threadIdx.x;
    wp[d] = Wpr0[d * NUM_REL + rr];
    __syncthreads();
    float s1 = 0.0f, s2 = 0.0f;
    const float* wmr = Wmr1 + (size_t)(rr * HID + d) * HID;
    const float* wpr = Wpr1 + d * HID;
    for (int k = 0; k < HID; k++) { s1 += wp[k] * wmr[k]; s2 += wp[k] * wpr[k]; }
    diag1[rr * HID + d] = s1;
    outrel[rr * HID + d] = s2;
}

// Wb slots: 0..49 = bf16(Wme1), 50 = bf16(Wres1)
__global__ __launch_bounds__(256) void k_wconv(const float* __restrict__ Wme1,
                                               const float* __restrict__ Wres1,
                                               unsigned short* __restrict__ Wb) {
    int i = blockIdx.x * 256 + threadIdx.x;
    if (i < NSLOT * HID * HID)
        Wb[i] = f2bf(i < NUM_REL * HID * HID ? Wme1[i] : Wres1[i - NUM_REL * HID * HID]);
}

// ============================================================
// layer 0 table: P[e*RS + slot*64 + d] = bf16(src[d][e] + diag0[slot][d])
// slot<50: src = Wme0 relation block; slot 50: src = Wres0
// ============================================================

__global__ __launch_bounds__(256) void k_transpose(const float* __restrict__ Wme0,
                                                   const float* __restrict__ Wres0,
                                                   const float* __restrict__ diag0,
                                                   unsigned short* __restrict__ P,
                                                   int RS) {
    __shared__ float tile[64][ETILE + 1];
    __shared__ float dg[64];
    int slot = blockIdx.x;
    int e0 = blockIdx.y * ETILE;
    int tid = threadIdx.x;
    if (tid < 64) dg[tid] = diag0[slot * HID + tid];
    const float* Wbase = (slot < NUM_REL)
        ? Wme0 + (size_t)(slot * HID) * NUM_ENT + e0
        : Wres0 + e0;
    bool full = (e0 + ETILE <= NUM_ENT);
    if (full) {
#pragma unroll
        for (int it = 0; it < 8; ++it) {
            int i2 = tid + it * 256;          // float4 index; 32 per d-row
            int dd = i2 >> 5;
            int x4 = (i2 & 31) * 4;
            float4 v = *(const float4*)(Wbase + (size_t)dd * NUM_ENT + x4);
            tile[dd][x4 + 0] = v.x; tile[dd][x4 + 1] = v.y;
            tile[dd][x4 + 2] = v.z; tile[dd][x4 + 3] = v.w;
        }
    } else {
        for (int i = tid; i < 64 * ETILE; i += 256) {
            int dd = i >> 7, xx = i & (ETILE - 1);
            tile[dd][xx] = (e0 + xx < NUM_ENT) ? Wbase[(size_t)dd * NUM_ENT + xx] : 0.f;
        }
    }
    __syncthreads();
    if (full) {
#pragma unroll
        for (int it = 0; it < 4; ++it) {
            int idx = tid + it * 256;         // short8 index; 8 per e-row
            int ee = idx >> 3;
            int d0 = (idx & 7) * 8;
            unsigned short pk[8];
#pragma unroll
            for (int k = 0; k < 8; ++k) pk[k] = f2bf(tile[d0 + k][ee] + dg[d0 + k]);
            *(short8*)&P[(size_t)(e0 + ee) * RS + (size_t)slot * 64 + d0] =
                *(const short8*)pk;
        }
    } else {
        for (int i = tid; i < 64 * ETILE; i += 256) {
            int ee = i >> 6, dd = i & 63;
            int e = e0 + ee;
            if (e < NUM_ENT)
                P[(size_t)e * RS + (size_t)slot * 64 + dd] = f2bf(tile[dd][ee] + dg[dd]);
        }
    }
}

// ============================================================
// layer 1 table (MFMA): B[e, slot*64+d] = bf16(Abf[e,:].Wb[slot][d,:] + diag1[slot,d])
// slot 50 = Abf.Wres1^T (diag1[50]=0)
// ============================================================

__global__ __launch_bounds__(256) void k_gemmB(const unsigned short* __restrict__ Abf,
                                               const unsigned short* __restrict__ Wb,
                                               const float* __restrict__ diag1,
                                               unsigned short* __restrict__ B,
                                               int RS, int percut) {
    int e0 = blockIdx.x * 64;
    int rl0 = blockIdx.y * percut;
    int rl1 = rl0 + percut;
    if (rl1 > NSLOT) rl1 = NSLOT;
    int w = (int)threadIdx.x >> 6;
    int lane = (int)threadIdx.x & 63;
    int lrow = lane & 15;
    int hi = lane >> 4;
    int lk8 = hi * 8;
    int row = e0 + w * 16 + lrow;
    int rowc = row < NUM_ENT ? row : NUM_ENT - 1;
    short8 a0 = ld8(Abf + (size_t)rowc * HID + lk8);
    short8 a1 = ld8(Abf + (size_t)rowc * HID + 32 + lk8);

    for (int rl = rl0; rl < rl1; ++rl) {
        const unsigned short* wb = Wb + (size_t)rl * 4096;
        f32x4 acc[4] = {};
#pragma unroll
        for (int tt = 0; tt < 4; ++tt) {
            const unsigned short* wd = wb + (tt * 16 + lrow) * 64;
            short8 b0 = ld8(wd + lk8);
            short8 b1 = ld8(wd + 32 + lk8);
            acc[tt] = __builtin_amdgcn_mfma_f32_16x16x32_bf16(a0, b0, acc[tt], 0, 0, 0);
            acc[tt] = __builtin_amdgcn_mfma_f32_16x16x32_bf16(a1, b1, acc[tt], 0, 0, 0);
        }
#pragma unroll
        for (int tt = 0; tt < 4; ++tt) {
            float dgv = diag1[rl * HID + tt * 16 + lrow];
#pragma unroll
            for (int q = 0; q < 4; ++q) {
                int eo = e0 + w * 16 + hi * 4 + q;
                if (eo < NUM_ENT)
                    B[(size_t)eo * RS + rl * 64 + tt * 16 + lrow] = f2bf(acc[tt][q] + dgv);
            }
        }
    }
}

// ============================================================
// tail-owned gather: v[e,:] = lrelu( sum_j table[off_j,:] + table[e,slot50,:] )
// 8-lane groups: one short8 (16B) per lane covers a 128B row per instr (8 rows/wave)
// ============================================================

__global__ __launch_bounds__(256) void k_scatter(const unsigned short* __restrict__ table,
                                                 const int* __restrict__ toff,
                                                 const unsigned* __restrict__ bucket2,
                                                 unsigned short* __restrict__ Abf,
                                                 float* __restrict__ outF,
                                                 int RS, int writeBf) {
    int e = __builtin_amdgcn_readfirstlane(blockIdx.x * 4 + (threadIdx.x >> 6));
    if (e >= NUM_ENT) return;
    int lane = threadIdx.x & 63;
    int oct = lane >> 3;     // 0..7 : which triplet row in the batch of 8
    int sl = lane & 7;       // d-slice: d = 8*sl .. 8*sl+7
    int j0 = toff[e], j1 = toff[e + 1];
    float acc[8] = {};
    int jj = j0;
    for (; jj + 8 <= j1; jj += 8) {
        unsigned o = bucket2[jj + oct];
        short8 v = ld8(table + o + sl * 8);
#pragma unroll
        for (int k = 0; k < 8; ++k) acc[k] += bf2f(((const unsigned short*)&v)[k]);
    }
    if (oct < j1 - jj) {
        unsigned o = bucket2[jj + oct];
        short8 v = ld8(table + o + sl * 8);
#pragma unroll
        for (int k = 0; k < 8; ++k) acc[k] += bf2f(((const unsigned short*)&v)[k]);
    }
#pragma unroll
    for (int k = 0; k < 8; ++k) {
        acc[k] += __shfl_xor(acc[k], 8);
        acc[k] += __shfl_xor(acc[k], 16);
        acc[k] += __shfl_xor(acc[k], 32);
    }
    if (oct == 0) {
        short8 base = ld8(table + (size_t)e * RS + (size_t)(NSLOT - 1) * 64 + sl * 8);
        float v[8];
#pragma unroll
        for (int k = 0; k < 8; ++k) {
            float x = acc[k] + bf2f(((const unsigned short*)&base)[k]);
            v[k] = (x >= 0.f) ? x : 0.01f * x;
        }
        if (writeBf) {
            unsigned short pk[8];
#pragma unroll
            for (int k = 0; k < 8; ++k) pk[k] = f2bf(v[k]);
            *(short8*)&Abf[(size_t)e * HID + sl * 8] = *(const short8*)pk;
        } else {
            *(float4*)&outF[(size_t)e * HID + sl * 8] = make_float4(v[0], v[1], v[2], v[3]);
            *(float4*)&outF[(size_t)e * HID + sl * 8 + 4] = make_float4(v[4], v[5], v[6], v[7]);
        }
    }
}

// ============================================================
// fallback path (round-1 atomic kernels) — used only if ws too small
// ============================================================

__global__ void k_hist(const int* __restrict__ r, int* __restrict__ hist) {
    __shared__ int lh[NUM_REL];
    int tid = threadIdx.x;
    if (tid < NUM_REL) lh[tid] = 0;
    __syncthreads();
    int i = blockIdx.x * blockDim.x + tid;
    if (i < NTRIP) atomicAdd(&lh[r[i]], 1);
    __syncthreads();
    if (tid < NUM_REL && lh[tid] > 0) atomicAdd(&hist[tid], lh[tid]);
}

__global__ void k_scan_small(const int* __restrict__ hist, int* __restrict__ off,
                             int* __restrict__ cur) {
    if (threadIdx.x == 0 && blockIdx.x == 0) {
        int s = 0;
        for (int i = 0; i < NUM_REL; i++) { off[i] = s; cur[i] = s; s += hist[i]; }
        off[NUM_REL] = s;
    }
}

__global__ void k_bucket(const int* __restrict__ h, const int* __restrict__ r,
                         const int* __restrict__ t, int* __restrict__ cur,
                         int2* __restrict__ bucket) {
    __shared__ int lcnt[NUM_REL];
    __shared__ int lbase[NUM_REL];
    int tid = threadIdx.x;
    if (tid < NUM_REL) lcnt[tid] = 0;
    __syncthreads();
    int i = blockIdx.x * blockDim.x + tid;
    int rr = -1, lpos = 0;
    if (i < NTRIP) { rr = r[i]; lpos = atomicAdd(&lcnt[rr], 1); }
    __syncthreads();
    if (tid < NUM_REL && lcnt[tid] > 0) lbase[tid] = atomicAdd(&cur[tid], lcnt[tid]);
    __syncthreads();
    if (i < NTRIP) bucket[lbase[rr] + lpos] = make_int2(h[i], t[i]);
}

__global__ void k_l0(const float* __restrict__ Wme0, const float* __restrict__ Wmr0,
                     const int* __restrict__ off, const int2* __restrict__ bucket,
                     float* __restrict__ U0) {
    __shared__ float row[NUM_ENT];
    int rr = blockIdx.x >> 6;
    int d  = blockIdx.x & 63;
    const float4* src4 = (const float4*)(Wme0 + (size_t)(rr * HID + d) * NUM_ENT);
    float4* row4 = (float4*)row;
    for (int i = threadIdx.x; i < NUM_ENT / 4; i += blockDim.x) row4[i] = src4[i];
    __syncthreads();
    float wd0 = Wmr0[(size_t)(rr * HID + d) * NUM_REL + rr];
    int b0 = off[rr], b1 = off[rr + 1];
    for (int i = b0 + threadIdx.x; i < b1; i += blockDim.x) {
        int2 ht = bucket[i];
        atomicAdd(&U0[(size_t)ht.y * HID + d], row[ht.x] + wd0);
    }
}

__global__ void k_lrelu(float* __restrict__ x, int n) {
    int i = blockIdx.x * blockDim.x + threadIdx.x;
    if (i < n) { float v = x[i]; x[i] = v >= 0.0f ? v : 0.01f * v; }
}

__global__ void k_init_u1(const float* __restrict__ A, const float* __restrict__ Wres1,
                          float* __restrict__ out) {
    __shared__ float W[HID][HID + 1];
    int tid = threadIdx.x;
    for (int i = tid; i < HID * HID; i += 256) W[i >> 6][i & 63] = Wres1[i];
    __syncthreads();
    int g = blockIdx.x * 256 + tid;
    int e = g >> 6, d = g & 63;
    if (e >= NUM_ENT) return;
    const float4* arow = (const float4*)(A + (size_t)e * HID);
    float acc = 0.0f;
#pragma unroll
    for (int k4 = 0; k4 < 16; k4++) {
        float4 a = arow[k4];
        acc = fmaf(a.x, W[d][k4 * 4 + 0], acc);
        acc = fmaf(a.y, W[d][k4 * 4 + 1], acc);
        acc = fmaf(a.z, W[d][k4 * 4 + 2], acc);
        acc = fmaf(a.w, W[d][k4 * 4 + 3], acc);
    }
    out[g] = acc;
}

#define L1_CHUNKS 16
__global__ void k_l1(const float* __restrict__ A, const float* __restrict__ Wme1,
                     const int* __restrict__ off, const int2* __restrict__ bucket,
                     const float* __restrict__ diag1, float* __restrict__ out) {
    int rr = blockIdx.x / L1_CHUNKS;
    int chunk = blockIdx.x % L1_CHUNKS;
    int b0 = off[rr], b1 = off[rr + 1];
    for (int i = b0 + chunk * 256 + (int)threadIdx.x; i < b1; i += L1_CHUNKS * 256) {
        int2 ht = bucket[i];
        const float4* arow = (const float4*)(A + (size_t)ht.x * HID);
        float4 a[16];
#pragma unroll
        for (int j = 0; j < 16; j++) a[j] = arow[j];
        float* op = out + (size_t)ht.y * HID;
#pragma unroll 4
        for (int d = 0; d < HID; d++) {
            const float4* m4 = (const float4*)(Wme1 + (size_t)(rr * HID + d) * HID);
            float acc = diag1[rr * HID + d];
#pragma unroll
            for (int k = 0; k < 16; k++) {
                float4 m = m4[k];
                acc = fmaf(a[k].x, m.x, acc);
                acc = fmaf(a[k].y, m.y, acc);
                acc = fmaf(a[k].z, m.z, acc);
                acc = fmaf(a[k].w, m.w, acc);
            }
            atomicAdd(op + d, acc);
        }
    }
}

// ============================================================
// launch
// ============================================================

static inline size_t align_up(size_t x, size_t a) { return (x + a - 1) & ~(a - 1); }

extern "C" void kernel_launch(void* const* d_in, const int* in_sizes, int n_in,
                              void* d_out, int out_size, void* d_ws, size_t ws_size,
                              hipStream_t stream) {
    const float* Wres0 = (const float*)d_in[0];
    const float* Wme0  = (const float*)d_in[1];
    const float* Wmr0  = (const float*)d_in[2];
    const float* Wpr0  = (const float*)d_in[3];
    const float* Wres1 = (const float*)d_in[4];
    const float* Wme1  = (const float*)d_in[5];
    const float* Wmr1  = (const float*)d_in[6];
    const float* Wpr1  = (const float*)d_in[7];
    const int* h = (const int*)d_in[8];
    const int* r = (const int*)d_in[9];
    const int* t = (const int*)d_in[10];
    float* out = (float*)d_out;  // [640000 ent | 3200 rel]

    char* ws = (char*)d_ws;
    const int nbt = (NTRIP + 255) / 256;       // 1954
    const int net = (NUM_ENT + 63) / 64;       // 157
    const int RS = NSLOT * 64;                 // 3264

    // workspace layout (fast path)
    size_t p = 0;
    size_t oTab  = p; p += align_up((size_t)NSLOT * 64 * NUM_ENT * 2, 256);  // 65.28 MB
    size_t oB2   = p; p += align_up((size_t)NTRIP * 4, 256);
    size_t oToff = p; p += align_up(((size_t)NUM_ENT + 1) * 4, 256);
    size_t oBins = p; p += align_up((size_t)NUM_ENT * 4, 256);
    size_t oRank = p; p += align_up((size_t)NTRIP * 4, 256);
    size_t oAbf  = p; p += align_up((size_t)NUM_ENT * HID * 2, 256);
    size_t oD0   = p; p += align_up((size_t)NSLOT * HID * 4, 256);
    size_t oD1   = p; p += align_up((size_t)NSLOT * HID * 4, 256);
    size_t oWb   = p; p += align_up((size_t)NSLOT * HID * HID * 2, 256);
    size_t need = p;

    if (need <= ws_size) {
        unsigned short* Tab = (unsigned short*)(ws + oTab);   // P then B
        unsigned* bucket2   = (unsigned*)(ws + oB2);
        int*      toff      = (int*)(ws + oToff);
        int*      bins      = (int*)(ws + oBins);
        int*      rank      = (int*)(ws + oRank);
        unsigned short* Abf = (unsigned short*)(ws + oAbf);
        float*    diag0     = (float*)(ws + oD0);
        float*    diag1     = (float*)(ws + oD1);
        unsigned short* Wb  = (unsigned short*)(ws + oWb);
        const int netile = (NUM_ENT + ETILE - 1) / ETILE;     // 79
        const int nsplit = 6;
        const int percut = (NSLOT + nsplit - 1) / nsplit;     // 9

        // ---- bucketing (one atomic pass) ----
        k_zero<<<(NUM_ENT + 255) / 256, 256, 0, stream>>>(bins, NUM_ENT);
        k_rank<<<nbt, 256, 0, stream>>>(t, bins, rank);
        k_scan<<<1, 1024, 0, stream>>>(bins, toff, NUM_ENT);
        k_fill<<<nbt, 256, 0, stream>>>(h, r, t, rank, toff, bucket2, RS);

        // ---- prep ----
        k_diag0<<<(NSLOT * HID + 255) / 256, 256, 0, stream>>>(Wmr0, diag0);
        k_rel<<<NUM_REL, HID, 0, stream>>>(Wpr0, Wmr1, Wpr1, diag1, out + NUM_ENT * HID);
        k_zero<<<1, 256, 0, stream>>>((int*)(diag1 + NUM_REL * HID), HID);  // diag1[50]=0
        k_wconv<<<(NSLOT * HID * HID + 255) / 256, 256, 0, stream>>>(Wme1, Wres1, Wb);

        // ---- layer 0: build P (51 slots) then gather ----
        k_transpose<<<dim3(NSLOT, netile), 256, 0, stream>>>(Wme0, Wres0, diag0, Tab, RS);
        k_scatter<<<(NUM_ENT + 3) / 4, 256, 0, stream>>>(
            Tab, toff, bucket2, Abf, out, RS, 1);    // writes Abf (bf16 A)

        // ---- layer 1: build B (51 slots, MFMA) then gather ----
        k_gemmB<<<dim3(net, nsplit), 256, 0, stream>>>(Abf, Wb, diag1, Tab, RS, percut);
        k_scatter<<<(NUM_ENT + 3) / 4, 256, 0, stream>>>(
            Tab, toff, bucket2, Abf, out, RS, 0);    // writes out (fp32)
        return;
    }

    // ---------- fallback: round-1 atomic path ----------
    {
        int2*  bucket = (int2*)ws;                    // 4,000,000 B
        float* U0     = (float*)(ws + 4000000);       // 2,560,000 B
        float* diag1  = (float*)(ws + 6560000);       // 12,800 B
        int*   hist   = (int*)(ws + 6572800);
        int*   off    = (int*)(ws + 6573056);
        int*   cur    = (int*)(ws + 6573312);

        hipMemsetAsync(hist, 0, NUM_REL * sizeof(int), stream);
        k_hist<<<nbt, 256, 0, stream>>>(r, hist);
        k_scan_small<<<1, 64, 0, stream>>>(hist, off, cur);
        k_bucket<<<nbt, 256, 0, stream>>>(h, r, t, cur, bucket);

        // U0[e,d] = Wres0[d,e] via strided writes (slow but correct)
        k_l0<<<NUM_REL * HID, 256, 0, stream>>>(Wme0, Wmr0, off, bucket, U0);
        // add Wres0^T then lrelu
        // (reuse k_init_u1-style: simple add kernel not available; fold via k_l0 init)
        // NOTE: fallback retains round-1 semantics: init U0 first
        // -- for safety, recompute with init + l0 order:
        // (kept identical to round-1 proven path)
        k_lrelu<<<(NUM_ENT * HID + 255) / 256, 256, 0, stream>>>(U0, NUM_ENT * HID);

        k_rel<<<NUM_REL, HID, 0, stream>>>(Wpr0, Wmr1, Wpr1, diag1, out + NUM_ENT * HID);
        k_init_u1<<<(NUM_ENT * HID) / 256, 256, 0, stream>>>(U0, Wres1, out);
        k_l1<<<NUM_REL * L1_CHUNKS, 256, 0, stream>>>(U0, Wme1, off, bucket, diag1, out);
        k_lrelu<<<(NUM_ENT * HID + 255) / 256, 256, 0, stream>>>(out, NUM_ENT * HID);
    }
}

// Round 8
// 183.187 us; speedup vs baseline: 2.2527x; 1.0602x over previous
//
#include <hip/hip_runtime.h>

#define NUM_ENT 10000
#define NUM_REL 50
#define HID 64
#define NTRIP 500000
#define NSLOT 51            // 50 relations + residual slot
#define ETILE 128

typedef __attribute__((ext_vector_type(8))) short short8;
typedef __attribute__((ext_vector_type(4))) float f32x4;

// bf16 helpers (RNE)
static __device__ __forceinline__ unsigned short f2bf(float x) {
    unsigned u = __float_as_uint(x);
    return (unsigned short)((u + 0x7FFFu + ((u >> 16) & 1u)) >> 16);
}
static __device__ __forceinline__ float bf2f(unsigned short b) {
    return __uint_as_float((unsigned)b << 16);
}
static __device__ __forceinline__ short8 ld8(const unsigned short* p) {
    return *(const short8*)p;
}

// ============================================================
// bucketing: one atomic pass (rank+count), scan, non-atomic fill
// ============================================================

__global__ __launch_bounds__(256) void k_zero(int* __restrict__ p, int n) {
    int i = blockIdx.x * 256 + threadIdx.x;
    if (i < n) p[i] = 0;
}

__global__ __launch_bounds__(256) void k_rank(const int* __restrict__ t,
                                              int* __restrict__ bins,
                                              int* __restrict__ rank) {
    int i = blockIdx.x * 256 + threadIdx.x;
    if (i < NTRIP) rank[i] = atomicAdd(&bins[t[i]], 1);
}

__global__ __launch_bounds__(1024) void k_scan(const int* __restrict__ bins,
                                               int* __restrict__ toff, int nbins) {
    __shared__ int wsum[16];
    int tid = threadIdx.x, lane = tid & 63, w = tid >> 6;
    int running = 0;
    for (int base = 0; base < nbins; base += 1024) {
        int i = base + tid;
        int s = (i < nbins) ? bins[i] : 0;
        int v = s;
        for (int off = 1; off < 64; off <<= 1) {
            int u = __shfl_up(v, off);
            if (lane >= off) v += u;
        }
        if (lane == 63) wsum[w] = v;
        __syncthreads();
        int woff = 0, tot = 0;
#pragma unroll
        for (int k = 0; k < 16; ++k) {
            int x = wsum[k];
            woff += (k < w) ? x : 0;
            tot += x;
        }
        int excl = running + woff + (v - s);
        if (i < nbins) toff[i] = excl;
        running += tot;
        __syncthreads();
    }
    if (tid == 0) toff[nbins] = running;
}

__global__ __launch_bounds__(256) void k_fill(const int* __restrict__ h,
                                              const int* __restrict__ r,
                                              const int* __restrict__ t,
                                              const int* __restrict__ rank,
                                              const int* __restrict__ toff,
                                              unsigned* __restrict__ bucket2, int RS) {
    int i = blockIdx.x * 256 + threadIdx.x;
    if (i < NTRIP)
        bucket2[toff[t[i]] + rank[i]] =
            (unsigned)h[i] * (unsigned)RS + (unsigned)r[i] * 64u;
}

// ============================================================
// small prep kernels
// ============================================================

// diag0[s*64+d] = Wmr0[(s*64+d)*50 + s] for s<50, 0 for slot 50
__global__ void k_diag0(const float* __restrict__ Wmr0, float* __restrict__ diag0) {
    int i = blockIdx.x * 256 + threadIdx.x;
    if (i < NSLOT * HID)
        diag0[i] = (i < NUM_REL * HID) ? Wmr0[(size_t)i * NUM_REL + (i >> 6)] : 0.f;
}

// diag1[r,d]; outrel[r,d]  (r<50)
__global__ void k_rel(const float* __restrict__ Wpr0, const float* __restrict__ Wmr1,
                      const float* __restrict__ Wpr1, float* __restrict__ diag1,
                      float* __restrict__ outrel) {
    __shared__ float wp[HID];
    int rr = blockIdx.x, d = threadIdx.x;
    wp[d] = Wpr0[d * NUM_REL + rr];
    __syncthreads();
    float s1 = 0.0f, s2 = 0.0f;
    const float* wmr = Wmr1 + (size_t)(rr * HID + d) * HID;
    const float* wpr = Wpr1 + d * HID;
    for (int k = 0; k < HID; k++) { s1 += wp[k] * wmr[k]; s2 += wp[k] * wpr[k]; }
    diag1[rr * HID + d] = s1;
    outrel[rr * HID + d] = s2;
}

// Wb slots: 0..49 = bf16(Wme1), 50 = bf16(Wres1)
__global__ __launch_bounds__(256) void k_wconv(const float* __restrict__ Wme1,
                                               const float* __restrict__ Wres1,
                                               unsigned short* __restrict__ Wb) {
    int i = blockIdx.x * 256 + threadIdx.x;
    if (i < NSLOT * HID * HID)
        Wb[i] = f2bf(i < NUM_REL * HID * HID ? Wme1[i] : Wres1[i - NUM_REL * HID * HID]);
}

// ============================================================
// layer 0 table: P[e*RS + slot*64 + d] = bf16(src[d][e] + diag0[slot][d])
// packed-uint LDS tile: uint[128][32], d-pairs packed, block-XOR swizzle.
// write: 16 scalar ds_write_b32; read: 4 ds_read_b128 (16B-aligned).
// ============================================================

__global__ __launch_bounds__(256) void k_transpose(const float* __restrict__ Wme0,
                                                   const float* __restrict__ Wres0,
                                                   const float* __restrict__ diag0,
                                                   unsigned short* __restrict__ P,
                                                   int RS) {
    __shared__ __align__(16) unsigned utile[ETILE][32];   // 16 KB
    __shared__ float dg[64];
    int slot = blockIdx.x;
    int e0 = blockIdx.y * ETILE;
    int tid = threadIdx.x;
    if (tid < 64) dg[tid] = diag0[slot * HID + tid];
    const float* Wbase = (slot < NUM_REL)
        ? Wme0 + (size_t)(slot * HID) * NUM_ENT + e0
        : Wres0 + e0;
    __syncthreads();

    if (e0 + ETILE <= NUM_ENT) {
        // ---- pack phase: 8 coalesced float4 loads, 16 ds_write_b32 ----
        int dp = tid >> 5;            // 0..7
        int x4 = (tid & 31) * 4;      // e-offset within tile
#pragma unroll
        for (int it = 0; it < 4; ++it) {
            int d = it * 16 + dp * 2;
            int d2 = it * 8 + dp;     // packed column (logical)
            float4 vA = *(const float4*)(Wbase + (size_t)d * NUM_ENT + x4);
            float4 vB = *(const float4*)(Wbase + (size_t)(d + 1) * NUM_ENT + x4);
            float dgA = dg[d], dgB = dg[d + 1];
            const float* a = (const float*)&vA;
            const float* b = (const float*)&vB;
#pragma unroll
            for (int j = 0; j < 4; ++j) {
                int e = x4 + j;
                int col = (((d2 >> 2) ^ (e & 7)) << 2) | (d2 & 3);
                utile[e][col] = (unsigned)f2bf(a[j] + dgA) |
                                ((unsigned)f2bf(b[j] + dgB) << 16);
            }
        }
        __syncthreads();
        // ---- store phase: 4 ds_read_b128 + 4 global dwordx4 stores ----
#pragma unroll
        for (int it = 0; it < 4; ++it) {
            int idx = tid + it * 256;     // 0..1023
            int ee = idx >> 3;
            int q = idx & 7;              // logical 4-uint block = d 8q..8q+7
            int blk = q ^ (ee & 7);
            uint4 u = *(const uint4*)&utile[ee][blk * 4];
            *(uint4*)&P[(size_t)(e0 + ee) * RS + (size_t)slot * 64 + q * 8] = u;
        }
    } else {
        // partial tail tile (16 rows): scalar path
        int rem = NUM_ENT - e0;
        for (int i = tid; i < rem * 64; i += 256) {
            int ee = i % rem;
            int dd = i / rem;
            float v = Wbase[(size_t)dd * NUM_ENT + ee] + dg[dd];
            P[(size_t)(e0 + ee) * RS + (size_t)slot * 64 + dd] = f2bf(v);
        }
    }
}

// ============================================================
// layer 1 table (MFMA): B[e, slot*64+d] = bf16(Abf[e,:].Wb[slot][d,:] + diag1[slot,d])
// ============================================================

__global__ __launch_bounds__(256) void k_gemmB(const unsigned short* __restrict__ Abf,
                                               const unsigned short* __restrict__ Wb,
                                               const float* __restrict__ diag1,
                                               unsigned short* __restrict__ B,
                                               int RS, int percut) {
    int e0 = blockIdx.x * 64;
    int rl0 = blockIdx.y * percut;
    int rl1 = rl0 + percut;
    if (rl1 > NSLOT) rl1 = NSLOT;
    int w = (int)threadIdx.x >> 6;
    int lane = (int)threadIdx.x & 63;
    int lrow = lane & 15;
    int hi = lane >> 4;
    int lk8 = hi * 8;
    int row = e0 + w * 16 + lrow;
    int rowc = row < NUM_ENT ? row : NUM_ENT - 1;
    short8 a0 = ld8(Abf + (size_t)rowc * HID + lk8);
    short8 a1 = ld8(Abf + (size_t)rowc * HID + 32 + lk8);

    for (int rl = rl0; rl < rl1; ++rl) {
        const unsigned short* wb = Wb + (size_t)rl * 4096;
        f32x4 acc[4] = {};
#pragma unroll
        for (int tt = 0; tt < 4; ++tt) {
            const unsigned short* wd = wb + (tt * 16 + lrow) * 64;
            short8 b0 = ld8(wd + lk8);
            short8 b1 = ld8(wd + 32 + lk8);
            acc[tt] = __builtin_amdgcn_mfma_f32_16x16x32_bf16(a0, b0, acc[tt], 0, 0, 0);
            acc[tt] = __builtin_amdgcn_mfma_f32_16x16x32_bf16(a1, b1, acc[tt], 0, 0, 0);
        }
#pragma unroll
        for (int tt = 0; tt < 4; ++tt) {
            float dgv = diag1[rl * HID + tt * 16 + lrow];
#pragma unroll
            for (int q = 0; q < 4; ++q) {
                int eo = e0 + w * 16 + hi * 4 + q;
                if (eo < NUM_ENT)
                    B[(size_t)eo * RS + rl * 64 + tt * 16 + lrow] = f2bf(acc[tt][q] + dgv);
            }
        }
    }
}

// ============================================================
// tail-owned gather: v[e,:] = lrelu( sum_j table[off_j,:] + table[e,slot50,:] )
// 8-lane groups; 2-deep unrolled (two independent 16B gathers in flight)
// ============================================================

__global__ __launch_bounds__(256) void k_scatter(const unsigned short* __restrict__ table,
                                                 const int* __restrict__ toff,
                                                 const unsigned* __restrict__ bucket2,
                                                 unsigned short* __restrict__ Abf,
                                                 float* __restrict__ outF,
                                                 int RS, int writeBf) {
    int e = __builtin_amdgcn_readfirstlane(blockIdx.x * 4 + (threadIdx.x >> 6));
    if (e >= NUM_ENT) return;
    int lane = threadIdx.x & 63;
    int oct = lane >> 3;     // which triplet row in the batch of 8
    int sl = lane & 7;       // d-slice: d = 8*sl .. 8*sl+7
    int j0 = toff[e], j1 = toff[e + 1];
    float acc[8] = {};
    float acc2[8] = {};
    int jj = j0;
    for (; jj + 16 <= j1; jj += 16) {
        unsigned o0 = bucket2[jj + oct];
        unsigned o1 = bucket2[jj + 8 + oct];
        short8 v0 = ld8(table + o0 + sl * 8);
        short8 v1 = ld8(table + o1 + sl * 8);
#pragma unroll
        for (int k = 0; k < 8; ++k) {
            acc[k]  += bf2f(((const unsigned short*)&v0)[k]);
            acc2[k] += bf2f(((const unsigned short*)&v1)[k]);
        }
    }
    if (jj + 8 <= j1) {
        unsigned o = bucket2[jj + oct];
        short8 v = ld8(table + o + sl * 8);
#pragma unroll
        for (int k = 0; k < 8; ++k) acc[k] += bf2f(((const unsigned short*)&v)[k]);
        jj += 8;
    }
    if (oct < j1 - jj) {
        unsigned o = bucket2[jj + oct];
        short8 v = ld8(table + o + sl * 8);
#pragma unroll
        for (int k = 0; k < 8; ++k) acc2[k] += bf2f(((const unsigned short*)&v)[k]);
    }
#pragma unroll
    for (int k = 0; k < 8; ++k) {
        acc[k] += acc2[k];
        acc[k] += __shfl_xor(acc[k], 8);
        acc[k] += __shfl_xor(acc[k], 16);
        acc[k] += __shfl_xor(acc[k], 32);
    }
    if (oct == 0) {
        short8 base = ld8(table + (size_t)e * RS + (size_t)(NSLOT - 1) * 64 + sl * 8);
        float v[8];
#pragma unroll
        for (int k = 0; k < 8; ++k) {
            float x = acc[k] + bf2f(((const unsigned short*)&base)[k]);
            v[k] = (x >= 0.f) ? x : 0.01f * x;
        }
        if (writeBf) {
            unsigned short pk[8];
#pragma unroll
            for (int k = 0; k < 8; ++k) pk[k] = f2bf(v[k]);
            *(short8*)&Abf[(size_t)e * HID + sl * 8] = *(const short8*)pk;
        } else {
            *(float4*)&outF[(size_t)e * HID + sl * 8] = make_float4(v[0], v[1], v[2], v[3]);
            *(float4*)&outF[(size_t)e * HID + sl * 8 + 4] = make_float4(v[4], v[5], v[6], v[7]);
        }
    }
}

// ============================================================
// fallback path (round-1 atomic kernels) — used only if ws too small
// ============================================================

__global__ void k_init_u0(const float* __restrict__ Wres0, float* __restrict__ U0) {
    __shared__ float tile[64][65];
    int e0 = blockIdx.x * 64;
    for (int i = threadIdx.x; i < 64 * 64; i += 256) {
        int dd = i >> 6, xx = i & 63;
        if (e0 + xx < NUM_ENT) tile[xx][dd] = Wres0[dd * NUM_ENT + e0 + xx];
    }
    __syncthreads();
    for (int i = threadIdx.x; i < 64 * 64; i += 256) {
        int ee = i >> 6, dd = i & 63;
        if (e0 + ee < NUM_ENT) U0[(e0 + ee) * HID + dd] = tile[ee][dd];
    }
}

__global__ void k_hist(const int* __restrict__ r, int* __restrict__ hist) {
    __shared__ int lh[NUM_REL];
    int tid = threadIdx.x;
    if (tid < NUM_REL) lh[tid] = 0;
    __syncthreads();
    int i = blockIdx.x * blockDim.x + tid;
    if (i < NTRIP) atomicAdd(&lh[r[i]], 1);
    __syncthreads();
    if (tid < NUM_REL && lh[tid] > 0) atomicAdd(&hist[tid], lh[tid]);
}

__global__ void k_scan_small(const int* __restrict__ hist, int* __restrict__ off,
                             int* __restrict__ cur) {
    if (threadIdx.x == 0 && blockIdx.x == 0) {
        int s = 0;
        for (int i = 0; i < NUM_REL; i++) { off[i] = s; cur[i] = s; s += hist[i]; }
        off[NUM_REL] = s;
    }
}

__global__ void k_bucket(const int* __restrict__ h, const int* __restrict__ r,
                         const int* __restrict__ t, int* __restrict__ cur,
                         int2* __restrict__ bucket) {
    __shared__ int lcnt[NUM_REL];
    __shared__ int lbase[NUM_REL];
    int tid = threadIdx.x;
    if (tid < NUM_REL) lcnt[tid] = 0;
    __syncthreads();
    int i = blockIdx.x * blockDim.x + tid;
    int rr = -1, lpos = 0;
    if (i < NTRIP) { rr = r[i]; lpos = atomicAdd(&lcnt[rr], 1); }
    __syncthreads();
    if (tid < NUM_REL && lcnt[tid] > 0) lbase[tid] = atomicAdd(&cur[tid], lcnt[tid]);
    __syncthreads();
    if (i < NTRIP) bucket[lbase[rr] + lpos] = make_int2(h[i], t[i]);
}

__global__ void k_l0(const float* __restrict__ Wme0, const float* __restrict__ Wmr0,
                     const int* __restrict__ off, const int2* __restrict__ bucket,
                     float* __restrict__ U0) {
    __shared__ float row[NUM_ENT];
    int rr = blockIdx.x >> 6;
    int d  = blockIdx.x & 63;
    const float4* src4 = (const float4*)(Wme0 + (size_t)(rr * HID + d) * NUM_ENT);
    float4* row4 = (float4*)row;
    for (int i = threadIdx.x; i < NUM_ENT / 4; i += blockDim.x) row4[i] = src4[i];
    __syncthreads();
    float wd0 = Wmr0[(size_t)(rr * HID + d) * NUM_REL + rr];
    int b0 = off[rr], b1 = off[rr + 1];
    for (int i = b0 + threadIdx.x; i < b1; i += blockDim.x) {
        int2 ht = bucket[i];
        atomicAdd(&U0[(size_t)ht.y * HID + d], row[ht.x] + wd0);
    }
}

__global__ void k_lrelu(float* __restrict__ x, int n) {
    int i = blockIdx.x * blockDim.x + threadIdx.x;
    if (i < n) { float v = x[i]; x[i] = v >= 0.0f ? v : 0.01f * v; }
}

__global__ void k_init_u1(const float* __restrict__ A, const float* __restrict__ Wres1,
                          float* __restrict__ out) {
    __shared__ float W[HID][HID + 1];
    int tid = threadIdx.x;
    for (int i = tid; i < HID * HID; i += 256) W[i >> 6][i & 63] = Wres1[i];
    __syncthreads();
    int g = blockIdx.x * 256 + tid;
    int e = g >> 6, d = g & 63;
    if (e >= NUM_ENT) return;
    const float4* arow = (const float4*)(A + (size_t)e * HID);
    float acc = 0.0f;
#pragma unroll
    for (int k4 = 0; k4 < 16; k4++) {
        float4 a = arow[k4];
        acc = fmaf(a.x, W[d][k4 * 4 + 0], acc);
        acc = fmaf(a.y, W[d][k4 * 4 + 1], acc);
        acc = fmaf(a.z, W[d][k4 * 4 + 2], acc);
        acc = fmaf(a.w, W[d][k4 * 4 + 3], acc);
    }
    out[g] = acc;
}

#define L1_CHUNKS 16
__global__ void k_l1(const float* __restrict__ A, const float* __restrict__ Wme1,
                     const int* __restrict__ off, const int2* __restrict__ bucket,
                     const float* __restrict__ diag1, float* __restrict__ out) {
    int rr = blockIdx.x / L1_CHUNKS;
    int chunk = blockIdx.x % L1_CHUNKS;
    int b0 = off[rr], b1 = off[rr + 1];
    for (int i = b0 + chunk * 256 + (int)threadIdx.x; i < b1; i += L1_CHUNKS * 256) {
        int2 ht = bucket[i];
        const float4* arow = (const float4*)(A + (size_t)ht.x * HID);
        float4 a[16];
#pragma unroll
        for (int j = 0; j < 16; j++) a[j] = arow[j];
        float* op = out + (size_t)ht.y * HID;
#pragma unroll 4
        for (int d = 0; d < HID; d++) {
            const float4* m4 = (const float4*)(Wme1 + (size_t)(rr * HID + d) * HID);
            float acc = diag1[rr * HID + d];
#pragma unroll
            for (int k = 0; k < 16; k++) {
                float4 m = m4[k];
                acc = fmaf(a[k].x, m.x, acc);
                acc = fmaf(a[k].y, m.y, acc);
                acc = fmaf(a[k].z, m.z, acc);
                acc = fmaf(a[k].w, m.w, acc);
            }
            atomicAdd(op + d, acc);
        }
    }
}

// ============================================================
// launch
// ============================================================

static inline size_t align_up(size_t x, size_t a) { return (x + a - 1) & ~(a - 1); }

extern "C" void kernel_launch(void* const* d_in, const int* in_sizes, int n_in,
                              void* d_out, int out_size, void* d_ws, size_t ws_size,
                              hipStream_t stream) {
    const float* Wres0 = (const float*)d_in[0];
    const float* Wme0  = (const float*)d_in[1];
    const float* Wmr0  = (const float*)d_in[2];
    const float* Wpr0  = (const float*)d_in[3];
    const float* Wres1 = (const float*)d_in[4];
    const float* Wme1  = (const float*)d_in[5];
    const float* Wmr1  = (const float*)d_in[6];
    const float* Wpr1  = (const float*)d_in[7];
    const int* h = (const int*)d_in[8];
    const int* r = (const int*)d_in[9];
    const int* t = (const int*)d_in[10];
    float* out = (float*)d_out;  // [640000 ent | 3200 rel]

    char* ws = (char*)d_ws;
    const int nbt = (NTRIP + 255) / 256;       // 1954
    const int net = (NUM_ENT + 63) / 64;       // 157
    const int RS = NSLOT * 64;                 // 3264

    // workspace layout (fast path)
    size_t p = 0;
    size_t oTab  = p; p += align_up((size_t)NSLOT * 64 * NUM_ENT * 2, 256);  // 65.28 MB
    size_t oB2   = p; p += align_up((size_t)NTRIP * 4, 256);
    size_t oToff = p; p += align_up(((size_t)NUM_ENT + 1) * 4, 256);
    size_t oBins = p; p += align_up((size_t)NUM_ENT * 4, 256);
    size_t oRank = p; p += align_up((size_t)NTRIP * 4, 256);
    size_t oAbf  = p; p += align_up((size_t)NUM_ENT * HID * 2, 256);
    size_t oD0   = p; p += align_up((size_t)NSLOT * HID * 4, 256);
    size_t oD1   = p; p += align_up((size_t)NSLOT * HID * 4, 256);
    size_t oWb   = p; p += align_up((size_t)NSLOT * HID * HID * 2, 256);
    size_t need = p;

    if (need <= ws_size) {
        unsigned short* Tab = (unsigned short*)(ws + oTab);   // P then B
        unsigned* bucket2   = (unsigned*)(ws + oB2);
        int*      toff      = (int*)(ws + oToff);
        int*      bins      = (int*)(ws + oBins);
        int*      rank      = (int*)(ws + oRank);
        unsigned short* Abf = (unsigned short*)(ws + oAbf);
        float*    diag0     = (float*)(ws + oD0);
        float*    diag1     = (float*)(ws + oD1);
        unsigned short* Wb  = (unsigned short*)(ws + oWb);
        const int netile = (NUM_ENT + ETILE - 1) / ETILE;     // 79
        const int nsplit = 6;
        const int percut = (NSLOT + nsplit - 1) / nsplit;     // 9

        // ---- bucketing (one atomic pass) ----
        k_zero<<<(NUM_ENT + 255) / 256, 256, 0, stream>>>(bins, NUM_ENT);
        k_rank<<<nbt, 256, 0, stream>>>(t, bins, rank);
        k_scan<<<1, 1024, 0, stream>>>(bins, toff, NUM_ENT);
        k_fill<<<nbt, 256, 0, stream>>>(h, r, t, rank, toff, bucket2, RS);

        // ---- prep ----
        k_diag0<<<(NSLOT * HID + 255) / 256, 256, 0, stream>>>(Wmr0, diag0);
        k_rel<<<NUM_REL, HID, 0, stream>>>(Wpr0, Wmr1, Wpr1, diag1, out + NUM_ENT * HID);
        k_zero<<<1, 256, 0, stream>>>((int*)(diag1 + NUM_REL * HID), HID);  // diag1[50]=0
        k_wconv<<<(NSLOT * HID * HID + 255) / 256, 256, 0, stream>>>(Wme1, Wres1, Wb);

        // ---- layer 0: build P (51 slots) then gather ----
        k_transpose<<<dim3(NSLOT, netile), 256, 0, stream>>>(Wme0, Wres0, diag0, Tab, RS);
        k_scatter<<<(NUM_ENT + 3) / 4, 256, 0, stream>>>(
            Tab, toff, bucket2, Abf, out, RS, 1);    // writes Abf (bf16 A)

        // ---- layer 1: build B (51 slots, MFMA) then gather ----
        k_gemmB<<<dim3(net, nsplit), 256, 0, stream>>>(Abf, Wb, diag1, Tab, RS, percut);
        k_scatter<<<(NUM_ENT + 3) / 4, 256, 0, stream>>>(
            Tab, toff, bucket2, Abf, out, RS, 0);    // writes out (fp32)
        return;
    }

    // ---------- fallback: round-1 atomic path ----------
    {
        int2*  bucket = (int2*)ws;                    // 4,000,000 B
        float* U0     = (float*)(ws + 4000000);       // 2,560,000 B
        float* diag1  = (float*)(ws + 6560000);       // 12,800 B
        int*   hist   = (int*)(ws + 6572800);
        int*   off    = (int*)(ws + 6573056);
        int*   cur    = (int*)(ws + 6573312);

        hipMemsetAsync(hist, 0, NUM_REL * sizeof(int), stream);
        k_hist<<<nbt, 256, 0, stream>>>(r, hist);
        k_scan_small<<<1, 64, 0, stream>>>(hist, off, cur);
        k_bucket<<<nbt, 256, 0, stream>>>(h, r, t, cur, bucket);

        k_init_u0<<<net, 256, 0, stream>>>(Wres0, U0);
        k_l0<<<NUM_REL * HID, 256, 0, stream>>>(Wme0, Wmr0, off, bucket, U0);
        k_lrelu<<<(NUM_ENT * HID + 255) / 256, 256, 0, stream>>>(U0, NUM_ENT * HID);

        k_rel<<<NUM_REL, HID, 0, stream>>>(Wpr0, Wmr1, Wpr1, diag1, out + NUM_ENT * HID);
        k_init_u1<<<(NUM_ENT * HID) / 256, 256, 0, stream>>>(U0, Wres1, out);
        k_l1<<<NUM_REL * L1_CHUNKS, 256, 0, stream>>>(U0, Wme1, off, bucket, diag1, out);
        k_lrelu<<<(NUM_ENT * HID + 255) / 256, 256, 0, stream>>>(out, NUM_ENT * HID);
    }
}

// Round 9
// 172.577 us; speedup vs baseline: 2.3912x; 1.0615x over previous
//
#include <hip/hip_runtime.h>

#define NUM_ENT 10000
#define NUM_REL 50
#define HID 64
#define NTRIP 500000
#define NSLOT 51            // 50 relations + residual slot
#define ETILE 128
#define NETILE 79           // ceil(10000/128)
#define TRB (NSLOT * NETILE)   // 4029 transpose blocks

typedef __attribute__((ext_vector_type(8))) short short8;
typedef __attribute__((ext_vector_type(4))) float f32x4;

// bf16 helpers (RNE)
static __device__ __forceinline__ unsigned short f2bf(float x) {
    unsigned u = __float_as_uint(x);
    return (unsigned short)((u + 0x7FFFu + ((u >> 16) & 1u)) >> 16);
}
static __device__ __forceinline__ float bf2f(unsigned short b) {
    return __uint_as_float((unsigned)b << 16);
}
static __device__ __forceinline__ short8 ld8(const unsigned short* p) {
    return *(const short8*)p;
}

// ============================================================
// fused prep: zero(bins) | diag0 | rel(diag1,outrel) | wconv | diag1-tail
// ============================================================

__global__ __launch_bounds__(256) void k_prep(const float* __restrict__ Wmr0,
                                              const float* __restrict__ Wpr0,
                                              const float* __restrict__ Wmr1,
                                              const float* __restrict__ Wpr1,
                                              const float* __restrict__ Wme1,
                                              const float* __restrict__ Wres1,
                                              int* __restrict__ bins,
                                              float* __restrict__ diag0,
                                              float* __restrict__ diag1,
                                              float* __restrict__ outrel,
                                              unsigned short* __restrict__ Wb) {
    int bid = blockIdx.x, tid = threadIdx.x;
    if (bid < 40) {                       // zero bins (10000)
        int i = bid * 256 + tid;
        if (i < NUM_ENT) bins[i] = 0;
        return;
    }
    bid -= 40;
    if (bid < 13) {                       // diag0 (NSLOT*64)
        int i = bid * 256 + tid;
        if (i < NSLOT * HID)
            diag0[i] = (i < NUM_REL * HID) ? Wmr0[(size_t)i * NUM_REL + (i >> 6)] : 0.f;
        return;
    }
    bid -= 13;
    if (bid < 13) {                       // rel: 4 relations per block
        __shared__ float wp[4][64];
        int sub = tid >> 6, d = tid & 63;
        int rr = bid * 4 + sub;
        wp[sub][d] = (rr < NUM_REL) ? Wpr0[d * NUM_REL + rr] : 0.f;
        __syncthreads();
        if (rr < NUM_REL) {
            float s1 = 0.f, s2 = 0.f;
            const float* wmr = Wmr1 + (size_t)(rr * HID + d) * HID;
            const float* wpr = Wpr1 + d * HID;
            for (int k = 0; k < HID; k++) {
                s1 += wp[sub][k] * wmr[k];
                s2 += wp[sub][k] * wpr[k];
            }
            diag1[rr * HID + d] = s1;
            outrel[rr * HID + d] = s2;
        }
        return;
    }
    bid -= 13;
    if (bid < 816) {                      // Wb: bf16(Wme1) | bf16(Wres1)
        int i = bid * 256 + tid;
        if (i < NSLOT * HID * HID)
            Wb[i] = f2bf(i < NUM_REL * HID * HID ? Wme1[i]
                                                 : Wres1[i - NUM_REL * HID * HID]);
        return;
    }
    // diag1 tail (slot 50) = 0
    if (tid < HID) diag1[NUM_REL * HID + tid] = 0.f;
}

// ============================================================
// bucketing: rank (atomic), scan; fill is fused into k_build
// ============================================================

__global__ __launch_bounds__(256) void k_rank(const int* __restrict__ t,
                                              int* __restrict__ bins,
                                              int* __restrict__ rank) {
    int i = blockIdx.x * 256 + threadIdx.x;
    if (i < NTRIP) rank[i] = atomicAdd(&bins[t[i]], 1);
}

__global__ __launch_bounds__(1024) void k_scan(const int* __restrict__ bins,
                                               int* __restrict__ toff, int nbins) {
    __shared__ int wsum[16];
    int tid = threadIdx.x, lane = tid & 63, w = tid >> 6;
    int running = 0;
    for (int base = 0; base < nbins; base += 1024) {
        int i = base + tid;
        int s = (i < nbins) ? bins[i] : 0;
        int v = s;
        for (int off = 1; off < 64; off <<= 1) {
            int u = __shfl_up(v, off);
            if (lane >= off) v += u;
        }
        if (lane == 63) wsum[w] = v;
        __syncthreads();
        int woff = 0, tot = 0;
#pragma unroll
        for (int k = 0; k < 16; ++k) {
            int x = wsum[k];
            woff += (k < w) ? x : 0;
            tot += x;
        }
        int excl = running + woff + (v - s);
        if (i < nbins) toff[i] = excl;
        running += tot;
        __syncthreads();
    }
    if (tid == 0) toff[nbins] = running;
}

// ============================================================
// fused build: transpose P (blocks 0..TRB-1) + bucket fill (rest)
// ============================================================

__global__ __launch_bounds__(256) void k_build(const float* __restrict__ Wme0,
                                               const float* __restrict__ Wres0,
                                               const float* __restrict__ diag0,
                                               unsigned short* __restrict__ P,
                                               int RS,
                                               const int* __restrict__ h,
                                               const int* __restrict__ r,
                                               const int* __restrict__ t,
                                               const int* __restrict__ rank,
                                               const int* __restrict__ toff,
                                               unsigned* __restrict__ bucket2) {
    __shared__ __align__(16) unsigned utile[ETILE][32];   // 16 KB
    __shared__ float dg[64];
    int tid = threadIdx.x;

    if (blockIdx.x >= TRB) {
        // ---- bucket fill ----
        int i = ((int)blockIdx.x - TRB) * 256 + tid;
        if (i < NTRIP)
            bucket2[toff[t[i]] + rank[i]] =
                (unsigned)h[i] * (unsigned)RS + (unsigned)r[i] * 64u;
        return;
    }

    // ---- transpose ----
    int slot = blockIdx.x / NETILE;
    int ey = blockIdx.x - slot * NETILE;
    int e0 = ey * ETILE;
    if (tid < 64) dg[tid] = diag0[slot * HID + tid];
    const float* Wbase = (slot < NUM_REL)
        ? Wme0 + (size_t)(slot * HID) * NUM_ENT + e0
        : Wres0 + e0;
    __syncthreads();

    if (e0 + ETILE <= NUM_ENT) {
        int dp = tid >> 5;            // 0..7
        int x4 = (tid & 31) * 4;      // e-offset within tile
#pragma unroll
        for (int it = 0; it < 4; ++it) {
            int d = it * 16 + dp * 2;
            int d2 = it * 8 + dp;     // packed column (logical)
            float4 vA = *(const float4*)(Wbase + (size_t)d * NUM_ENT + x4);
            float4 vB = *(const float4*)(Wbase + (size_t)(d + 1) * NUM_ENT + x4);
            float dgA = dg[d], dgB = dg[d + 1];
            const float* a = (const float*)&vA;
            const float* b = (const float*)&vB;
#pragma unroll
            for (int j = 0; j < 4; ++j) {
                int e = x4 + j;
                int col = (((d2 >> 2) ^ (e & 7)) << 2) | (d2 & 3);
                utile[e][col] = (unsigned)f2bf(a[j] + dgA) |
                                ((unsigned)f2bf(b[j] + dgB) << 16);
            }
        }
        __syncthreads();
#pragma unroll
        for (int it = 0; it < 4; ++it) {
            int idx = tid + it * 256;     // 0..1023
            int ee = idx >> 3;
            int q = idx & 7;              // logical 4-uint block = d 8q..8q+7
            int blk = q ^ (ee & 7);
            uint4 u = *(const uint4*)&utile[ee][blk * 4];
            *(uint4*)&P[(size_t)(e0 + ee) * RS + (size_t)slot * 64 + q * 8] = u;
        }
    } else {
        int rem = NUM_ENT - e0;
        for (int i = tid; i < rem * 64; i += 256) {
            int ee = i % rem;
            int dd = i / rem;
            float v = Wbase[(size_t)dd * NUM_ENT + ee] + dg[dd];
            P[(size_t)(e0 + ee) * RS + (size_t)slot * 64 + dd] = f2bf(v);
        }
    }
}

// ============================================================
// layer 1 table (MFMA): B[e, slot*64+d] = bf16(Abf[e,:].Wb[slot][d,:] + diag1[slot,d])
// ============================================================

__global__ __launch_bounds__(256) void k_gemmB(const unsigned short* __restrict__ Abf,
                                               const unsigned short* __restrict__ Wb,
                                               const float* __restrict__ diag1,
                                               unsigned short* __restrict__ B,
                                               int RS, int percut) {
    int e0 = blockIdx.x * 64;
    int rl0 = blockIdx.y * percut;
    int rl1 = rl0 + percut;
    if (rl1 > NSLOT) rl1 = NSLOT;
    int w = (int)threadIdx.x >> 6;
    int lane = (int)threadIdx.x & 63;
    int lrow = lane & 15;
    int hi = lane >> 4;
    int lk8 = hi * 8;
    int row = e0 + w * 16 + lrow;
    int rowc = row < NUM_ENT ? row : NUM_ENT - 1;
    short8 a0 = ld8(Abf + (size_t)rowc * HID + lk8);
    short8 a1 = ld8(Abf + (size_t)rowc * HID + 32 + lk8);

    for (int rl = rl0; rl < rl1; ++rl) {
        const unsigned short* wb = Wb + (size_t)rl * 4096;
        f32x4 acc[4] = {};
#pragma unroll
        for (int tt = 0; tt < 4; ++tt) {
            const unsigned short* wd = wb + (tt * 16 + lrow) * 64;
            short8 b0 = ld8(wd + lk8);
            short8 b1 = ld8(wd + 32 + lk8);
            acc[tt] = __builtin_amdgcn_mfma_f32_16x16x32_bf16(a0, b0, acc[tt], 0, 0, 0);
            acc[tt] = __builtin_amdgcn_mfma_f32_16x16x32_bf16(a1, b1, acc[tt], 0, 0, 0);
        }
#pragma unroll
        for (int tt = 0; tt < 4; ++tt) {
            float dgv = diag1[rl * HID + tt * 16 + lrow];
#pragma unroll
            for (int q = 0; q < 4; ++q) {
                int eo = e0 + w * 16 + hi * 4 + q;
                if (eo < NUM_ENT)
                    B[(size_t)eo * RS + rl * 64 + tt * 16 + lrow] = f2bf(acc[tt][q] + dgv);
            }
        }
    }
}

// ============================================================
// tail-owned gather: v[e,:] = lrelu( sum_j table[off_j,:] + table[e,slot50,:] )
// ============================================================

__global__ __launch_bounds__(256) void k_scatter(const unsigned short* __restrict__ table,
                                                 const int* __restrict__ toff,
                                                 const unsigned* __restrict__ bucket2,
                                                 unsigned short* __restrict__ Abf,
                                                 float* __restrict__ outF,
                                                 int RS, int writeBf) {
    int e = __builtin_amdgcn_readfirstlane(blockIdx.x * 4 + (threadIdx.x >> 6));
    if (e >= NUM_ENT) return;
    int lane = threadIdx.x & 63;
    int oct = lane >> 3;     // which triplet row in the batch of 8
    int sl = lane & 7;       // d-slice: d = 8*sl .. 8*sl+7
    int j0 = toff[e], j1 = toff[e + 1];
    float acc[8] = {};
    float acc2[8] = {};
    int jj = j0;
    for (; jj + 16 <= j1; jj += 16) {
        unsigned o0 = bucket2[jj + oct];
        unsigned o1 = bucket2[jj + 8 + oct];
        short8 v0 = ld8(table + o0 + sl * 8);
        short8 v1 = ld8(table + o1 + sl * 8);
#pragma unroll
        for (int k = 0; k < 8; ++k) {
            acc[k]  += bf2f(((const unsigned short*)&v0)[k]);
            acc2[k] += bf2f(((const unsigned short*)&v1)[k]);
        }
    }
    if (jj + 8 <= j1) {
        unsigned o = bucket2[jj + oct];
        short8 v = ld8(table + o + sl * 8);
#pragma unroll
        for (int k = 0; k < 8; ++k) acc[k] += bf2f(((const unsigned short*)&v)[k]);
        jj += 8;
    }
    if (oct < j1 - jj) {
        unsigned o = bucket2[jj + oct];
        short8 v = ld8(table + o + sl * 8);
#pragma unroll
        for (int k = 0; k < 8; ++k) acc2[k] += bf2f(((const unsigned short*)&v)[k]);
    }
#pragma unroll
    for (int k = 0; k < 8; ++k) {
        acc[k] += acc2[k];
        acc[k] += __shfl_xor(acc[k], 8);
        acc[k] += __shfl_xor(acc[k], 16);
        acc[k] += __shfl_xor(acc[k], 32);
    }
    if (oct == 0) {
        short8 base = ld8(table + (size_t)e * RS + (size_t)(NSLOT - 1) * 64 + sl * 8);
        float v[8];
#pragma unroll
        for (int k = 0; k < 8; ++k) {
            float x = acc[k] + bf2f(((const unsigned short*)&base)[k]);
            v[k] = (x >= 0.f) ? x : 0.01f * x;
        }
        if (writeBf) {
            unsigned short pk[8];
#pragma unroll
            for (int k = 0; k < 8; ++k) pk[k] = f2bf(v[k]);
            *(short8*)&Abf[(size_t)e * HID + sl * 8] = *(const short8*)pk;
        } else {
            *(float4*)&outF[(size_t)e * HID + sl * 8] = make_float4(v[0], v[1], v[2], v[3]);
            *(float4*)&outF[(size_t)e * HID + sl * 8 + 4] = make_float4(v[4], v[5], v[6], v[7]);
        }
    }
}

// ============================================================
// fallback path (round-1 atomic kernels) — used only if ws too small
// ============================================================

__global__ void k_rel(const float* __restrict__ Wpr0, const float* __restrict__ Wmr1,
                      const float* __restrict__ Wpr1, float* __restrict__ diag1,
                      float* __restrict__ outrel) {
    __shared__ float wp[HID];
    int rr = blockIdx.x, d = threadIdx.x;
    wp[d] = Wpr0[d * NUM_REL + rr];
    __syncthreads();
    float s1 = 0.0f, s2 = 0.0f;
    const float* wmr = Wmr1 + (size_t)(rr * HID + d) * HID;
    const float* wpr = Wpr1 + d * HID;
    for (int k = 0; k < HID; k++) { s1 += wp[k] * wmr[k]; s2 += wp[k] * wpr[k]; }
    diag1[rr * HID + d] = s1;
    outrel[rr * HID + d] = s2;
}

__global__ void k_init_u0(const float* __restrict__ Wres0, float* __restrict__ U0) {
    __shared__ float tile[64][65];
    int e0 = blockIdx.x * 64;
    for (int i = threadIdx.x; i < 64 * 64; i += 256) {
        int dd = i >> 6, xx = i & 63;
        if (e0 + xx < NUM_ENT) tile[xx][dd] = Wres0[dd * NUM_ENT + e0 + xx];
    }
    __syncthreads();
    for (int i = threadIdx.x; i < 64 * 64; i += 256) {
        int ee = i >> 6, dd = i & 63;
        if (e0 + ee < NUM_ENT) U0[(e0 + ee) * HID + dd] = tile[ee][dd];
    }
}

__global__ void k_hist(const int* __restrict__ r, int* __restrict__ hist) {
    __shared__ int lh[NUM_REL];
    int tid = threadIdx.x;
    if (tid < NUM_REL) lh[tid] = 0;
    __syncthreads();
    int i = blockIdx.x * blockDim.x + tid;
    if (i < NTRIP) atomicAdd(&lh[r[i]], 1);
    __syncthreads();
    if (tid < NUM_REL && lh[tid] > 0) atomicAdd(&hist[tid], lh[tid]);
}

__global__ void k_scan_small(const int* __restrict__ hist, int* __restrict__ off,
                             int* __restrict__ cur) {
    if (threadIdx.x == 0 && blockIdx.x == 0) {
        int s = 0;
        for (int i = 0; i < NUM_REL; i++) { off[i] = s; cur[i] = s; s += hist[i]; }
        off[NUM_REL] = s;
    }
}

__global__ void k_bucket(const int* __restrict__ h, const int* __restrict__ r,
                         const int* __restrict__ t, int* __restrict__ cur,
                         int2* __restrict__ bucket) {
    __shared__ int lcnt[NUM_REL];
    __shared__ int lbase[NUM_REL];
    int tid = threadIdx.x;
    if (tid < NUM_REL) lcnt[tid] = 0;
    __syncthreads();
    int i = blockIdx.x * blockDim.x + tid;
    int rr = -1, lpos = 0;
    if (i < NTRIP) { rr = r[i]; lpos = atomicAdd(&lcnt[rr], 1); }
    __syncthreads();
    if (tid < NUM_REL && lcnt[tid] > 0) lbase[tid] = atomicAdd(&cur[tid], lcnt[tid]);
    __syncthreads();
    if (i < NTRIP) bucket[lbase[rr] + lpos] = make_int2(h[i], t[i]);
}

__global__ void k_l0(const float* __restrict__ Wme0, const float* __restrict__ Wmr0,
                     const int* __restrict__ off, const int2* __restrict__ bucket,
                     float* __restrict__ U0) {
    __shared__ float row[NUM_ENT];
    int rr = blockIdx.x >> 6;
    int d  = blockIdx.x & 63;
    const float4* src4 = (const float4*)(Wme0 + (size_t)(rr * HID + d) * NUM_ENT);
    float4* row4 = (float4*)row;
    for (int i = threadIdx.x; i < NUM_ENT / 4; i += blockDim.x) row4[i] = src4[i];
    __syncthreads();
    float wd0 = Wmr0[(size_t)(rr * HID + d) * NUM_REL + rr];
    int b0 = off[rr], b1 = off[rr + 1];
    for (int i = b0 + threadIdx.x; i < b1; i += blockDim.x) {
        int2 ht = bucket[i];
        atomicAdd(&U0[(size_t)ht.y * HID + d], row[ht.x] + wd0);
    }
}

__global__ void k_lrelu(float* __restrict__ x, int n) {
    int i = blockIdx.x * blockDim.x + threadIdx.x;
    if (i < n) { float v = x[i]; x[i] = v >= 0.0f ? v : 0.01f * v; }
}

__global__ void k_init_u1(const float* __restrict__ A, const float* __restrict__ Wres1,
                          float* __restrict__ out) {
    __shared__ float W[HID][HID + 1];
    int tid = threadIdx.x;
    for (int i = tid; i < HID * HID; i += 256) W[i >> 6][i & 63] = Wres1[i];
    __syncthreads();
    int g = blockIdx.x * 256 + tid;
    int e = g >> 6, d = g & 63;
    if (e >= NUM_ENT) return;
    const float4* arow = (const float4*)(A + (size_t)e * HID);
    float acc = 0.0f;
#pragma unroll
    for (int k4 = 0; k4 < 16; k4++) {
        float4 a = arow[k4];
        acc = fmaf(a.x, W[d][k4 * 4 + 0], acc);
        acc = fmaf(a.y, W[d][k4 * 4 + 1], acc);
        acc = fmaf(a.z, W[d][k4 * 4 + 2], acc);
        acc = fmaf(a.w, W[d][k4 * 4 + 3], acc);
    }
    out[g] = acc;
}

#define L1_CHUNKS 16
__global__ void k_l1(const float* __restrict__ A, const float* __restrict__ Wme1,
                     const int* __restrict__ off, const int2* __restrict__ bucket,
                     const float* __restrict__ diag1, float* __restrict__ out) {
    int rr = blockIdx.x / L1_CHUNKS;
    int chunk = blockIdx.x % L1_CHUNKS;
    int b0 = off[rr], b1 = off[rr + 1];
    for (int i = b0 + chunk * 256 + (int)threadIdx.x; i < b1; i += L1_CHUNKS * 256) {
        int2 ht = bucket[i];
        const float4* arow = (const float4*)(A + (size_t)ht.x * HID);
        float4 a[16];
#pragma unroll
        for (int j = 0; j < 16; j++) a[j] = arow[j];
        float* op = out + (size_t)ht.y * HID;
#pragma unroll 4
        for (int d = 0; d < HID; d++) {
            const float4* m4 = (const float4*)(Wme1 + (size_t)(rr * HID + d) * HID);
            float acc = diag1[rr * HID + d];
#pragma unroll
            for (int k = 0; k < 16; k++) {
                float4 m = m4[k];
                acc = fmaf(a[k].x, m.x, acc);
                acc = fmaf(a[k].y, m.y, acc);
                acc = fmaf(a[k].z, m.z, acc);
                acc = fmaf(a[k].w, m.w, acc);
            }
            atomicAdd(op + d, acc);
        }
    }
}

// ============================================================
// launch
// ============================================================

static inline size_t align_up(size_t x, size_t a) { return (x + a - 1) & ~(a - 1); }

extern "C" void kernel_launch(void* const* d_in, const int* in_sizes, int n_in,
                              void* d_out, int out_size, void* d_ws, size_t ws_size,
                              hipStream_t stream) {
    const float* Wres0 = (const float*)d_in[0];
    const float* Wme0  = (const float*)d_in[1];
    const float* Wmr0  = (const float*)d_in[2];
    const float* Wpr0  = (const float*)d_in[3];
    const float* Wres1 = (const float*)d_in[4];
    const float* Wme1  = (const float*)d_in[5];
    const float* Wmr1  = (const float*)d_in[6];
    const float* Wpr1  = (const float*)d_in[7];
    const int* h = (const int*)d_in[8];
    const int* r = (const int*)d_in[9];
    const int* t = (const int*)d_in[10];
    float* out = (float*)d_out;  // [640000 ent | 3200 rel]

    char* ws = (char*)d_ws;
    const int nbt = (NTRIP + 255) / 256;       // 1954
    const int net = (NUM_ENT + 63) / 64;       // 157
    const int RS = NSLOT * 64;                 // 3264

    // workspace layout (fast path)
    size_t p = 0;
    size_t oTab  = p; p += align_up((size_t)NSLOT * 64 * NUM_ENT * 2, 256);  // 65.28 MB
    size_t oB2   = p; p += align_up((size_t)NTRIP * 4, 256);
    size_t oToff = p; p += align_up(((size_t)NUM_ENT + 1) * 4, 256);
    size_t oBins = p; p += align_up((size_t)NUM_ENT * 4, 256);
    size_t oRank = p; p += align_up((size_t)NTRIP * 4, 256);
    size_t oAbf  = p; p += align_up((size_t)NUM_ENT * HID * 2, 256);
    size_t oD0   = p; p += align_up((size_t)NSLOT * HID * 4, 256);
    size_t oD1   = p; p += align_up((size_t)NSLOT * HID * 4, 256);
    size_t oWb   = p; p += align_up((size_t)NSLOT * HID * HID * 2, 256);
    size_t need = p;

    if (need <= ws_size) {
        unsigned short* Tab = (unsigned short*)(ws + oTab);   // P then B
        unsigned* bucket2   = (unsigned*)(ws + oB2);
        int*      toff      = (int*)(ws + oToff);
        int*      bins      = (int*)(ws + oBins);
        int*      rank      = (int*)(ws + oRank);
        unsigned short* Abf = (unsigned short*)(ws + oAbf);
        float*    diag0     = (float*)(ws + oD0);
        float*    diag1     = (float*)(ws + oD1);
        unsigned short* Wb  = (unsigned short*)(ws + oWb);
        const int nsplit = 6;
        const int percut = (NSLOT + nsplit - 1) / nsplit;     // 9

        // 1. fused prep
        k_prep<<<883, 256, 0, stream>>>(Wmr0, Wpr0, Wmr1, Wpr1, Wme1, Wres1,
                                        bins, diag0, diag1, out + NUM_ENT * HID, Wb);
        // 2-3. bucketing
        k_rank<<<nbt, 256, 0, stream>>>(t, bins, rank);
        k_scan<<<1, 1024, 0, stream>>>(bins, toff, NUM_ENT);
        // 4. fused transpose + bucket fill
        k_build<<<TRB + nbt, 256, 0, stream>>>(Wme0, Wres0, diag0, Tab, RS,
                                               h, r, t, rank, toff, bucket2);
        // 5. layer-0 gather -> Abf (bf16 A)
        k_scatter<<<(NUM_ENT + 3) / 4, 256, 0, stream>>>(
            Tab, toff, bucket2, Abf, out, RS, 1);
        // 6. layer-1 table (MFMA)
        k_gemmB<<<dim3(net, nsplit), 256, 0, stream>>>(Abf, Wb, diag1, Tab, RS, percut);
        // 7. layer-1 gather -> out
        k_scatter<<<(NUM_ENT + 3) / 4, 256, 0, stream>>>(
            Tab, toff, bucket2, Abf, out, RS, 0);
        return;
    }

    // ---------- fallback: round-1 atomic path ----------
    {
        int2*  bucket = (int2*)ws;                    // 4,000,000 B
        float* U0     = (float*)(ws + 4000000);       // 2,560,000 B
        float* diag1  = (float*)(ws + 6560000);       // 12,800 B
        int*   hist   = (int*)(ws + 6572800);
        int*   off    = (int*)(ws + 6573056);
        int*   cur    = (int*)(ws + 6573312);

        hipMemsetAsync(hist, 0, NUM_REL * sizeof(int), stream);
        k_hist<<<nbt, 256, 0, stream>>>(r, hist);
        k_scan_small<<<1, 64, 0, stream>>>(hist, off, cur);
        k_bucket<<<nbt, 256, 0, stream>>>(h, r, t, cur, bucket);

        k_init_u0<<<net, 256, 0, stream>>>(Wres0, U0);
        k_l0<<<NUM_REL * HID, 256, 0, stream>>>(Wme0, Wmr0, off, bucket, U0);
        k_lrelu<<<(NUM_ENT * HID + 255) / 256, 256, 0, stream>>>(U0, NUM_ENT * HID);

        k_rel<<<NUM_REL, HID, 0, stream>>>(Wpr0, Wmr1, Wpr1, diag1, out + NUM_ENT * HID);
        k_init_u1<<<(NUM_ENT * HID) / 256, 256, 0, stream>>>(U0, Wres1, out);
        k_l1<<<NUM_REL * L1_CHUNKS, 256, 0, stream>>>(U0, Wme1, off, bucket, diag1, out);
        k_lrelu<<<(NUM_ENT * HID + 255) / 256, 256, 0, stream>>>(out, NUM_ENT * HID);
    }
}